// Round 3
// baseline (356.697 us; speedup 1.0000x reference)
//
#include <hip/hip_runtime.h>
#include <math.h>
#include <stdint.h>

// MoE: E=8, top-2, D=512, H=2048, N=4096, fp32 in/out.
// Round 9: direct global->VGPR B-fragments (no B staging at all).
//   r8 post-mortem: counted vmcnt was NEUTRAL (158us, MfmaUtil 8.5%) -- the
//   barrier-lockstep staging structure is the limit, and B has ZERO cross-wave
//   reuse (each wave owns disjoint B rows), so LDS staging of B is pure
//   overhead + a DMA-alias hazard for the waitcnt pass.
//   v9 expert kernel: B frags loaded straight to VGPRs (same 16-rows x 64B
//   per-instruction coalescing as the staged loads), 4-slot rotating frag
//   buffer, prefetch distance 3. x-tile (32x512) staged ONCE to LDS
//   (chunk-swizzled); hT is the only other LDS. Barriers: 2 per si (hT
//   hand-off, raw s_barrier + lgkmcnt only) = 16 per block vs 512.
//   LDS ~50KB. counts-zeroing folded into prep (one less dispatch).

#define N_TOK 4096
#define D_IN  512
#define H_DIM 2048
#define N_EXP 8
#define TM    32
#define HS    256
#define MAXT  40                // covers cnt up to 1280 (expected ~1024)
#define YROWS (MAXT * TM)       // 1280 y slots per expert
#define HROW  264               // u16 stride: 528B rows, 16B-aligned

typedef float  f32x4  __attribute__((ext_vector_type(4)));
typedef short  short8 __attribute__((ext_vector_type(8)));
typedef unsigned short u16;

__device__ __forceinline__ u16 bf16_rne(float f) {
    uint32_t u = __float_as_uint(f);
    return (u16)((u + 0x7fffu + ((u >> 16) & 1u)) >> 16);
}
__device__ __forceinline__ void async16(const u16* g, u16* l) {
    __builtin_amdgcn_global_load_lds(
        (const __attribute__((address_space(1))) void*)g,
        (__attribute__((address_space(3))) void*)l, 16, 0, 0);
}

// ---------------------------------------------------------------------------
// Gate body: one wave per token.
// ---------------------------------------------------------------------------
__device__ __forceinline__ void gate_one(
    int n, int l,
    const float* __restrict__ x, const float* __restrict__ Wg,
    const float* __restrict__ bg, float* __restrict__ gates,
    int2* __restrict__ recE, float2* __restrict__ recG,
    u16* __restrict__ xb, int write_xb)
{
    const float* xr  = x + (size_t)n * D_IN + l * 8;
    const float* wgr = Wg + (size_t)l * 8 * N_EXP;

    float xv[8];
    *(float4*)&xv[0] = *(const float4*)xr;
    *(float4*)&xv[4] = *(const float4*)(xr + 4);

    if (write_xb) {
        short8 pk;
#pragma unroll
        for (int i = 0; i < 8; ++i) pk[i] = (short)bf16_rne(xv[i]);
        *(short8*)(xb + (size_t)n * D_IN + l * 8) = pk;
    }

    float acc[8] = {0.f, 0.f, 0.f, 0.f, 0.f, 0.f, 0.f, 0.f};
#pragma unroll
    for (int dd = 0; dd < 8; ++dd) {
        float4 wa = *(const float4*)(wgr + dd * N_EXP);
        float4 wb = *(const float4*)(wgr + dd * N_EXP + 4);
        acc[0] = fmaf(xv[dd], wa.x, acc[0]);
        acc[1] = fmaf(xv[dd], wa.y, acc[1]);
        acc[2] = fmaf(xv[dd], wa.z, acc[2]);
        acc[3] = fmaf(xv[dd], wa.w, acc[3]);
        acc[4] = fmaf(xv[dd], wb.x, acc[4]);
        acc[5] = fmaf(xv[dd], wb.y, acc[5]);
        acc[6] = fmaf(xv[dd], wb.z, acc[6]);
        acc[7] = fmaf(xv[dd], wb.w, acc[7]);
    }
#pragma unroll
    for (int off = 32; off >= 1; off >>= 1) {
#pragma unroll
        for (int e = 0; e < N_EXP; ++e)
            acc[e] += __shfl_xor(acc[e], off);
    }

    float g[8];
    float mx = -3.4e38f;
#pragma unroll
    for (int e = 0; e < N_EXP; ++e) { g[e] = acc[e] + bg[e]; mx = fmaxf(mx, g[e]); }
    float s = 0.f;
#pragma unroll
    for (int e = 0; e < N_EXP; ++e) { g[e] = expf(g[e] - mx); s += g[e]; }
    const float inv = 1.0f / s;
#pragma unroll
    for (int e = 0; e < N_EXP; ++e) g[e] *= inv;

    if (l == 0) {
        float* go = gates + (size_t)n * N_EXP;
        *(float4*)go       = make_float4(g[0], g[1], g[2], g[3]);
        *(float4*)(go + 4) = make_float4(g[4], g[5], g[6], g[7]);

        int e1 = 0; float g1 = g[0];
#pragma unroll
        for (int e = 1; e < N_EXP; ++e) if (g[e] > g1) { g1 = g[e]; e1 = e; }
        int e2 = -1; float g2 = -1.f;
#pragma unroll
        for (int e = 0; e < N_EXP; ++e) if (e != e1 && g[e] > g2) { g2 = g[e]; e2 = e; }

        recE[n] = make_int2(e1, e2);
        recG[n] = make_float2(g1, g2);
    }
}

// ---------------------------------------------------------------------------
// Prep: fused transpose-to-bf16 (blocks < nconv) + gating (blocks >= nconv).
// First gate block also zeroes counts (build_lists runs after prep).
// ---------------------------------------------------------------------------
__global__ __launch_bounds__(256) void moe_prep(
    const float* __restrict__ W1, const float* __restrict__ W2,
    u16* __restrict__ w1t, u16* __restrict__ w2t, int nconv,
    const float* __restrict__ x, const float* __restrict__ Wg,
    const float* __restrict__ bg, float* __restrict__ gates,
    int2* __restrict__ recE, float2* __restrict__ recG,
    u16* __restrict__ xb, int write_xb, int* __restrict__ counts)
{
    __shared__ u16 th[64][65];
    const int idx = blockIdx.x;
    if (idx < nconv) {
        const int z  = idx >> 8;            // 0..15
        const int e  = z & 7;
        const bool isW2 = z >= 8;
        const float* in = isW2 ? W2 : W1;
        u16* ob         = isW2 ? w2t : w1t;
        const int R = isW2 ? H_DIM : D_IN;
        const int C = isW2 ? D_IN : H_DIM;
        const size_t base = (size_t)e * R * C;
        const int rem = idx & 255;
        const int bx = rem & 31, by = rem >> 5;
        const int c0 = (isW2 ? by : bx) * 64;
        const int r0 = (isW2 ? bx : by) * 64;
        const int c  = threadIdx.x & 63, rq = threadIdx.x >> 6;

#pragma unroll
        for (int i = 0; i < 16; ++i) {
            int r = rq * 16 + i;
            th[r][c] = bf16_rne(in[base + (size_t)(r0 + r) * C + c0 + c]);
        }
        __syncthreads();
#pragma unroll
        for (int i = 0; i < 16; ++i) {
            int rw = rq * 16 + i;
            ob[base + (size_t)(c0 + rw) * R + r0 + c] = th[c][rw];
        }
    } else {
        const int g = idx - nconv;
        if (g == 0 && threadIdx.x < N_EXP) counts[threadIdx.x] = 0;
        const int n = g * 4 + (threadIdx.x >> 6);
        const int l = threadIdx.x & 63;
        gate_one(n, l, x, Wg, bg, gates, recE, recG, xb, write_xb);
    }
}

// ---------------------------------------------------------------------------
// List build: 64 blocks (expert e = bid>>3, 512-token chunk).
// ---------------------------------------------------------------------------
__global__ __launch_bounds__(256) void build_lists(
    const int2* __restrict__ recE, const float2* __restrict__ recG,
    int* __restrict__ counts, int* __restrict__ lists, float* __restrict__ cwA,
    int* __restrict__ slotRec)
{
    __shared__ int cnt, base;
    __shared__ int   ltok[512];
    __shared__ float lcw[512];
    __shared__ int   lsrc[512];
    const int e  = blockIdx.x >> 3;
    const int c0 = (blockIdx.x & 7) * 512;
    const int tid = threadIdx.x;
    if (tid == 0) cnt = 0;
    __syncthreads();
#pragma unroll
    for (int it = 0; it < 2; ++it) {
        int t = c0 + it * 256 + tid;
        int2   ee = recE[t];
        float2 gg = recG[t];
        if (ee.x == e) {
            int p = atomicAdd(&cnt, 1);
            ltok[p] = t;  lcw[p] = gg.x;  lsrc[p] = 2 * t;
        }
        if (ee.y == e) {
            int p = atomicAdd(&cnt, 1);
            ltok[p] = t;  lcw[p] = gg.y;  lsrc[p] = 2 * t + 1;
        }
    }
    __syncthreads();
    if (tid == 0) base = atomicAdd(&counts[e], cnt);
    __syncthreads();
    const int c = cnt, b0 = base;
    for (int i = tid; i < c; i += 256) {
        int p = b0 + i;
        lists[e * N_TOK + p] = ltok[i];
        cwA[e * N_TOK + p]   = lcw[i];
        if (slotRec) slotRec[lsrc[i]] = p;
    }
}

// ---------------------------------------------------------------------------
// v9 expert kernel: full-H per block, B frags direct global->VGPR.
//   e = blockIdx&7 (XCD affinity), t = blockIdx>>3. 4 waves, TM=32 tokens.
//   Per si: 32 steps (16 G1 + 16 G2), each {prefetch frag group p+3; 8 MFMA}.
//   x-tile in LDS (staged once, chunk-swizzled); hT in LDS; B never staged.
//   2 raw barriers per si around hT hand-off; no vmcnt games anywhere.
// ---------------------------------------------------------------------------
#define LD1G(base_, ks_, slot_)                                               \
    do {                                                                      \
        _Pragma("unroll")                                                     \
        for (int _nt = 0; _nt < 4; ++_nt)                                     \
            f[slot_][_nt] = *(const short8*)((base_) + off1[_nt] + (ks_) * 32); \
    } while (0)

#define LD2G(base_, u_, slot_)                                                \
    do {                                                                      \
        const int _nc = (u_) >> 2, _k2 = (u_) & 3;                            \
        _Pragma("unroll")                                                     \
        for (int _nt = 0; _nt < 2; ++_nt)                                     \
            _Pragma("unroll")                                                 \
            for (int _kk = 0; _kk < 2; ++_kk)                                 \
                f[slot_][_nt * 2 + _kk] = *(const short8*)((base_) + off2[_nt] \
                    + _nc * 262144 + _k2 * 64 + _kk * 32);                    \
    } while (0)

__global__ __launch_bounds__(256, 1) void moe_expert_mfma3(
    const u16* __restrict__ xb,
    const u16* __restrict__ w1t, const u16* __restrict__ w2t,
    const float* __restrict__ b1, const float* __restrict__ b2,
    float* __restrict__ y,
    const int* __restrict__ counts, const int* __restrict__ lists,
    const float* __restrict__ cwA)
{
    const int b = blockIdx.x;
    const int e = b & 7;            // expert -> XCD affinity
    const int t = b >> 3;
    int cnt = counts[e];
    if (cnt > YROWS) cnt = YROWS;
    if (t * TM >= cnt) return;

    __shared__ __align__(16) u16 xs[TM * 512];   // 32 KB, chunk-swizzled
    __shared__ __align__(16) u16 hT[TM * HROW];  // 16.5 KB
    __shared__ int   tokS[TM];
    __shared__ float cwS[TM];

    const int tid  = threadIdx.x;
    const int w    = tid >> 6;
    const int lane = tid & 63;
    const int quad = lane >> 4;
    const int l16  = lane & 15;

    if (tid < TM) {
        int gi = t * TM + tid;
        bool v = gi < cnt;
        tokS[tid] = v ? lists[e * N_TOK + gi] : 0;
        cwS[tid]  = v ? cwA[e * N_TOK + gi] : 0.f;   // cw=0 kills pad rows
    }
    __syncthreads();

    // ---- stage x-tile ONCE: xs[row][512], 16B-chunk swizzle key=(row>>2)&3.
    // dest linear (wave base + lane*16B); swizzle applied on SOURCE address.
#pragma unroll
    for (int j = 0; j < 8; ++j) {
        const int row = j * 4 + w;
        const u16* src = xb + (size_t)tokS[row] * D_IN
                       + (lane >> 2) * 32 + ((lane & 3) ^ (j & 3)) * 8;
        async16(src, xs + row * 512 + lane * 8);
    }

    // ---- fragment read offsets ----
    int fA1[2], fA2[2];
#pragma unroll
    for (int m = 0; m < 2; ++m) {
        fA1[m] = (m * 16 + l16) * 512 + (quad ^ ((l16 >> 2) & 3)) * 8;
        fA2[m] = (m * 16 + l16) * HROW + quad * 8;
    }

    // ---- direct B-frag global offsets (u16 units) ----
    const u16* w1E = w1t + (size_t)e * H_DIM * D_IN;
    const u16* w2E = w2t + (size_t)e * D_IN * H_DIM;
    int off1[4];
#pragma unroll
    for (int nt = 0; nt < 4; ++nt)
        off1[nt] = (w * 64 + nt * 16 + l16) * 512 + quad * 8;
    int off2[2];
#pragma unroll
    for (int nt = 0; nt < 2; ++nt)
        off2[nt] = (w * 32 + nt * 16 + l16) * 2048 + quad * 8;

    // ---- persistent output accumulator: y[32][512] ----
    f32x4 accY[4][2][2];
#pragma unroll
    for (int nc = 0; nc < 4; ++nc)
#pragma unroll
        for (int m = 0; m < 2; ++m)
#pragma unroll
            for (int nt = 0; nt < 2; ++nt)
                accY[nc][m][nt] = (f32x4){0.f, 0.f, 0.f, 0.f};

    short8 f[4][4];                 // 4-slot rotating frag buffer (64 VGPR)

    // prologue: prefetch si=0 steps 0..2
    LD1G(w1E, 0, 0);
    LD1G(w1E, 1, 1);
    LD1G(w1E, 2, 2);
    __syncthreads();                // drains xs staging; xs visible to all

    for (int si = 0; si < 8; ++si) {
        const u16* c1 = w1E + si * (HS * D_IN);     // G1 slice base
        const u16* c2 = w2E + si * HS;              // G2 col-slice base
        const u16* n1 = c1 + (HS * D_IN);           // next-si G1 base
        float b1v[4];
#pragma unroll
        for (int nt = 0; nt < 4; ++nt)
            b1v[nt] = b1[e * H_DIM + si * HS + w * 64 + nt * 16 + l16];

        f32x4 acc1[2][4];
#pragma unroll
        for (int m = 0; m < 2; ++m)
#pragma unroll
            for (int nt = 0; nt < 4; ++nt) acc1[m][nt] = (f32x4){0.f, 0.f, 0.f, 0.f};

#pragma unroll
        for (int p = 0; p < 32; ++p) {
            const int slot = (p + 3) & 3;
            // prefetch step p+3 (pure global->reg; freely crosses barriers)
            if (p < 13)       { LD1G(c1, p + 3, slot); }
            else if (p < 29)  { LD2G(c2, p - 13, slot); }
            else if (si < 7)  { LD1G(n1, p - 29, slot); }

            if (p < 16) {
                // ---- G1 step: h-slice += x @ W1T ----
                short8 af0 = *(const short8*)(xs + fA1[0] + p * 32);
                short8 af1 = *(const short8*)(xs + fA1[1] + p * 32);
                __builtin_amdgcn_s_setprio(1);
#pragma unroll
                for (int nt = 0; nt < 4; ++nt) {
                    acc1[0][nt] = __builtin_amdgcn_mfma_f32_16x16x32_bf16(
                        af0, f[p & 3][nt], acc1[0][nt], 0, 0, 0);
                    acc1[1][nt] = __builtin_amdgcn_mfma_f32_16x16x32_bf16(
                        af1, f[p & 3][nt], acc1[1][nt], 0, 0, 0);
                }
                __builtin_amdgcn_s_setprio(0);
            } else {
                if (p == 16) {
                    // hand-off: prev G2 readers done -> write hT -> visible
                    __builtin_amdgcn_s_barrier();
                    __builtin_amdgcn_sched_barrier(0);
#pragma unroll
                    for (int nt = 0; nt < 4; ++nt) {
                        const int c = w * 64 + nt * 16 + l16;
#pragma unroll
                        for (int m = 0; m < 2; ++m)
#pragma unroll
                            for (int r = 0; r < 4; ++r) {
                                int row = m * 16 + quad * 4 + r;
                                hT[row * HROW + c] =
                                    bf16_rne(fmaxf(acc1[m][nt][r] + b1v[nt], 0.f));
                            }
                    }
                    asm volatile("s_waitcnt lgkmcnt(0)" ::: "memory");
                    __builtin_amdgcn_s_barrier();
                    __builtin_amdgcn_sched_barrier(0);
                }
                // ---- G2 step: accY += hT @ W2T ----
                const int u = p - 16, nc = u >> 2, k2 = u & 3;
#pragma unroll
                for (int kk = 0; kk < 2; ++kk) {
                    short8 a0 = *(const short8*)(hT + fA2[0] + k2 * 64 + kk * 32);
                    short8 a1 = *(const short8*)(hT + fA2[1] + k2 * 64 + kk * 32);
                    __builtin_amdgcn_s_setprio(1);
                    accY[nc][0][0] = __builtin_amdgcn_mfma_f32_16x16x32_bf16(
                        a0, f[p & 3][kk],     accY[nc][0][0], 0, 0, 0);
                    accY[nc][1][0] = __builtin_amdgcn_mfma_f32_16x16x32_bf16(
                        a1, f[p & 3][kk],     accY[nc][1][0], 0, 0, 0);
                    accY[nc][0][1] = __builtin_amdgcn_mfma_f32_16x16x32_bf16(
                        a0, f[p & 3][2 + kk], accY[nc][0][1], 0, 0, 0);
                    accY[nc][1][1] = __builtin_amdgcn_mfma_f32_16x16x32_bf16(
                        a1, f[p & 3][2 + kk], accY[nc][1][1], 0, 0, 0);
                    __builtin_amdgcn_s_setprio(0);
                }
            }
        }
    }

    // -------- epilogue: dense y write: (acc + b2) * cw --------
    float* yT = y + ((size_t)e * YROWS + (size_t)t * TM) * D_IN;
#pragma unroll
    for (int nc = 0; nc < 4; ++nc)
#pragma unroll
        for (int nt = 0; nt < 2; ++nt) {
            const int dcol = nc * 128 + w * 32 + nt * 16 + l16;
            const float bias = b2[e * D_IN + dcol];
#pragma unroll
            for (int m = 0; m < 2; ++m)
#pragma unroll
                for (int r = 0; r < 4; ++r) {
                    const int row = m * 16 + quad * 4 + r;
                    yT[(size_t)row * D_IN + dcol] =
                        (accY[nc][m][nt][r] + bias) * cwS[row];
                }
        }
}

// ---------------------------------------------------------------------------
// Combine: out[t] = y[e1][slot1] + y[e2][slot2]   (cw, b2 already folded in).
// ---------------------------------------------------------------------------
__global__ __launch_bounds__(256) void moe_combine(
    const float* __restrict__ y, const int* __restrict__ slotRec,
    const int2* __restrict__ recE, float* __restrict__ out)
{
    const int t  = blockIdx.x * 2 + (threadIdx.x >> 7);
    const int c4 = (threadIdx.x & 127) << 2;
    const int2 ee = recE[t];
    int s1 = slotRec[2 * t + 0];
    int s2 = slotRec[2 * t + 1];
    s1 = s1 < YROWS ? s1 : YROWS - 1;   // safety clamp
    s2 = s2 < YROWS ? s2 : YROWS - 1;
    const float4 a  = *(const float4*)(y + ((size_t)ee.x * YROWS + s1) * D_IN + c4);
    const float4 bb = *(const float4*)(y + ((size_t)ee.y * YROWS + s2) * D_IN + c4);
    *(float4*)(out + (size_t)t * D_IN + c4) =
        make_float4(a.x + bb.x, a.y + bb.y, a.z + bb.z, a.w + bb.w);
}

// ---------------------------------------------------------------------------
// r6 single-pass bf16 expert kernel (known-passing) — fallback if ws < NEED2.
// ---------------------------------------------------------------------------
__global__ __launch_bounds__(256, 4) void moe_expert_mfma(
    const u16* __restrict__ xb,
    const u16* __restrict__ w1t, const u16* __restrict__ w2t,
    const float* __restrict__ b1, const float* __restrict__ b2,
    float* __restrict__ out,
    const int* __restrict__ counts, const int* __restrict__ lists,
    const float* __restrict__ cwA)
{
    const int b = blockIdx.x;
    const int s = b & 7;
    const int q = b >> 3;
    const int t = q % MAXT;
    const int e = q / MAXT;
    const int cnt = counts[e];
    if (t * TM >= cnt) return;

    __shared__ __align__(16) u16 sB[8192];
    __shared__ __align__(16) u16 sA[1024];
    __shared__ __align__(16) u16 hT[TM * HROW];
    __shared__ int   tokS[TM];
    __shared__ float cwS[TM];

    const int tid  = threadIdx.x;
    const int w    = tid >> 6;
    const int lane = tid & 63;
    const int quad = lane >> 4;
    const int l16  = lane & 15;

    if (tid < TM) {
        int gi = t * TM + tid;
        bool v = gi < cnt;
        tokS[tid] = v ? lists[e * N_TOK + gi] : 0;
        cwS[tid]  = v ? cwA[e * N_TOK + gi] : 0.f;
    }
    __syncthreads();

    const int r4   = lane >> 2;
    const int csw1 = (lane & 3) ^ ((lane >> 4) & 3);
    const int r8   = lane >> 3;
    const int csw2 = (lane & 7) ^ r8;
    u16* ldsB0 = sB + w * 2048 + lane * 8;
    u16* ldsA0 = sA + lane * 8;

    int fB1[4], fA1[2];
#pragma unroll
    for (int nt = 0; nt < 4; ++nt) {
        int r = w * 64 + nt * 16 + l16;
        fB1[nt] = r * 32 + (quad ^ ((l16 >> 2) & 3)) * 8;
    }
#pragma unroll
    for (int m = 0; m < 2; ++m) {
        int r = m * 16 + l16;
        fA1[m] = r * 32 + (quad ^ ((l16 >> 2) & 3)) * 8;
    }
    int fB2[2][2], fA2[2];
#pragma unroll
    for (int nt = 0; nt < 2; ++nt)
#pragma unroll
        for (int kk = 0; kk < 2; ++kk) {
            int r = w * 32 + nt * 16 + l16;
            fB2[nt][kk] = r * 64 + (((kk * 4 + quad) ^ (l16 & 7)) * 8);
        }
#pragma unroll
    for (int m = 0; m < 2; ++m)
        fA2[m] = (m * 16 + l16) * HROW + quad * 8;

    int bOffB[4];
#pragma unroll
    for (int i = 0; i < 4; ++i)
        bOffB[i] = (s * HS + w * 64 + i * 16 + r4) * D_IN + csw1 * 8;
    int aOff0 = tokS[r4]      * D_IN + csw1 * 8;
    int aOff1 = tokS[16 + r4] * D_IN + csw1 * 8;
    const u16* w1E = w1t + (size_t)e * H_DIM * D_IN;

    f32x4 acc1[2][4];
#pragma unroll
    for (int m = 0; m < 2; ++m)
#pragma unroll
        for (int nt = 0; nt < 4; ++nt) acc1[m][nt] = (f32x4){0.f, 0.f, 0.f, 0.f};

    for (int ks = 0; ks < 16; ++ks) {
        const int kb = ks * 32;
        __syncthreads();
#pragma unroll
        for (int i = 0; i < 4; ++i)
            async16(w1E + bOffB[i] + kb, ldsB0 + i * 512);
        if (w == 0) {
            async16(xb + aOff0 + kb, ldsA0);
            async16(xb + aOff1 + kb, ldsA0 + 512);
        }
        __syncthreads();
        short8 bf[4], af[2];
#pragma unroll
        for (int nt = 0; nt < 4; ++nt) bf[nt] = *(const short8*)(sB + fB1[nt]);
#pragma unroll
        for (int m = 0; m < 2; ++m)  af[m] = *(const short8*)(sA + fA1[m]);
#pragma unroll
        for (int nt = 0; nt < 4; ++nt)
#pragma unroll
            for (int m = 0; m < 2; ++m)
                acc1[m][nt] = __builtin_amdgcn_mfma_f32_16x16x32_bf16(af[m], bf[nt], acc1[m][nt], 0, 0, 0);
    }

#pragma unroll
    for (int nt = 0; nt < 4; ++nt) {
        const int c = w * 64 + nt * 16 + l16;
        const float bias = b1[e * H_DIM + s * HS + c];
#pragma unroll
        for (int m = 0; m < 2; ++m)
#pragma unroll
            for (int r = 0; r < 4; ++r) {
                int row = m * 16 + quad * 4 + r;
                hT[row * HROW + c] = bf16_rne(fmaxf(acc1[m][nt][r] + bias, 0.f));
            }
    }

    const u16* w2E = w2t + (size_t)e * D_IN * H_DIM;
    int bOff2[4];
#pragma unroll
    for (int i = 0; i < 4; ++i)
        bOff2[i] = (w * 32 + i * 8 + r8) * H_DIM + s * HS + csw2 * 8;

    for (int nc = 0; nc < 4; ++nc) {
        f32x4 acc2[2][2];
#pragma unroll
        for (int m = 0; m < 2; ++m)
#pragma unroll
            for (int nt = 0; nt < 2; ++nt) acc2[m][nt] = (f32x4){0.f, 0.f, 0.f, 0.f};

        for (int ks = 0; ks < 4; ++ks) {
            __syncthreads();
#pragma unroll
            for (int i = 0; i < 4; ++i)
                async16(w2E + bOff2[i] + nc * (128 * H_DIM) + ks * 64,
                        ldsB0 + i * 512);
            __syncthreads();
#pragma unroll
            for (int kk = 0; kk < 2; ++kk) {
                short8 a0  = *(const short8*)(hT + fA2[0] + ks * 64 + kk * 32);
                short8 a1  = *(const short8*)(hT + fA2[1] + ks * 64 + kk * 32);
                short8 b0  = *(const short8*)(sB + fB2[0][kk]);
                short8 b1f = *(const short8*)(sB + fB2[1][kk]);
                acc2[0][0] = __builtin_amdgcn_mfma_f32_16x16x32_bf16(a0, b0,  acc2[0][0], 0, 0, 0);
                acc2[1][0] = __builtin_amdgcn_mfma_f32_16x16x32_bf16(a1, b0,  acc2[1][0], 0, 0, 0);
                acc2[0][1] = __builtin_amdgcn_mfma_f32_16x16x32_bf16(a0, b1f, acc2[0][1], 0, 0, 0);
                acc2[1][1] = __builtin_amdgcn_mfma_f32_16x16x32_bf16(a1, b1f, acc2[1][1], 0, 0, 0);
            }
        }

#pragma unroll
        for (int nt = 0; nt < 2; ++nt) {
            const int dcol = nc * 128 + w * 32 + nt * 16 + l16;
            const float bias = (s == 0) ? b2[e * D_IN + dcol] : 0.f;
#pragma unroll
            for (int m = 0; m < 2; ++m)
#pragma unroll
                for (int r = 0; r < 4; ++r) {
                    int row = m * 16 + quad * 4 + r;
                    float v = (acc2[m][nt][r] + bias) * cwS[row];
                    atomicAdd(out + (size_t)tokS[row] * D_IN + dcol, v);
                }
        }
    }
}

// ---------------------------------------------------------------------------
// Fallback fp32 expert kernel (round 1, known-passing) — used if ws too small.
// ---------------------------------------------------------------------------
__global__ __launch_bounds__(256, 4) void moe_expert_fp32(
    const float* __restrict__ x,  const float* __restrict__ W1,
    const float* __restrict__ b1, const float* __restrict__ W2,
    const float* __restrict__ b2, float* __restrict__ out,
    const int* __restrict__ counts, const int* __restrict__ lists,
    const float* __restrict__ cwA)
{
    const int e    = blockIdx.x & 7;
    const int tile = blockIdx.x >> 3;
    const int cnt  = counts[e];
    if (tile * 16 >= cnt) return;

    __shared__ float xs[16 * 520];
    __shared__ float hs[16 * 68];
    __shared__ int   tokS[16];
    __shared__ float cwS[16];

    const int tid = threadIdx.x;
    if (tid < 16) {
        int gi = tile * 16 + tid;
        bool v = gi < cnt;
        tokS[tid] = v ? lists[e * N_TOK + gi] : 0;
        cwS[tid]  = v ? cwA[e * N_TOK + gi]  : 0.f;
    }
    __syncthreads();
    {
        const int i = tid >> 4, p = tid & 15;
        const float* xr = x + (size_t)tokS[i] * D_IN + p * 32;
        float* xd = xs + i * 520 + p * 32;
#pragma unroll
        for (int qq = 0; qq < 8; ++qq)
            *(float4*)(xd + qq * 4) = *(const float4*)(xr + qq * 4);
    }
    __syncthreads();

    const float* W1e = W1 + (size_t)e * D_IN * H_DIM;
    const float* W2e = W2 + (size_t)e * H_DIM * D_IN;
    const int j = tid & 31, rg1 = tid >> 5, cg = tid & 63, rg2 = tid >> 6;

    float acc[4][8];
#pragma unroll
    for (int i = 0; i < 4; ++i)
#pragma unroll
        for (int m = 0; m < 8; ++m) acc[i][m] = 0.f;

    for (int hc = 0; hc < H_DIM / 64; ++hc) {
        float a1[2][2] = {{0.f, 0.f}, {0.f, 0.f}};
        const float* w1p = W1e + hc * 64 + j;
        for (int d = 0; d < D_IN; d += 4) {
            float xv[2][4];
            *(float4*)xv[0] = *(const float4*)(xs + (rg1 * 2 + 0) * 520 + d);
            *(float4*)xv[1] = *(const float4*)(xs + (rg1 * 2 + 1) * 520 + d);
#pragma unroll
            for (int dd = 0; dd < 4; ++dd) {
                float wa = w1p[(size_t)(d + dd) * H_DIM];
                float wb = w1p[(size_t)(d + dd) * H_DIM + 32];
                a1[0][0] = fmaf(xv[0][dd], wa, a1[0][0]);
                a1[0][1] = fmaf(xv[0][dd], wb, a1[0][1]);
                a1[1][0] = fmaf(xv[1][dd], wa, a1[1][0]);
                a1[1][1] = fmaf(xv[1][dd], wb, a1[1][1]);
            }
        }
        float b1a = b1[e * H_DIM + hc * 64 + j];
        float b1b = b1[e * H_DIM + hc * 64 + j + 32];
        __syncthreads();
        hs[(rg1 * 2 + 0) * 68 + j]      = fmaxf(a1[0][0] + b1a, 0.f);
        hs[(rg1 * 2 + 0) * 68 + j + 32] = fmaxf(a1[0][1] + b1b, 0.f);
        hs[(rg1 * 2 + 1) * 68 + j]      = fmaxf(a1[1][0] + b1a, 0.f);
        hs[(rg1 * 2 + 1) * 68 + j + 32] = fmaxf(a1[1][1] + b1b, 0.f);
        __syncthreads();
        const float* w2p = W2e + (size_t)(hc * 64) * D_IN + cg;
        for (int k = 0; k < 64; k += 4) {
            float hv[4][4];
#pragma unroll
            for (int i = 0; i < 4; ++i)
                *(float4*)hv[i] = *(const float4*)(hs + (rg2 * 4 + i) * 68 + k);
#pragma unroll
            for (int kk = 0; kk < 4; ++kk) {
                float w2r[8];
#pragma unroll
                for (int m = 0; m < 8; ++m)
                    w2r[m] = w2p[(size_t)(k + kk) * D_IN + 64 * m];
#pragma unroll
                for (int i = 0; i < 4; ++i)
#pragma unroll
                    for (int m = 0; m < 8; ++m)
                        acc[i][m] = fmaf(hv[i][kk], w2r[m], acc[i][m]);
            }
        }
        __syncthreads();
    }
    float b2v[8];
#pragma unroll
    for (int m = 0; m < 8; ++m) b2v[m] = b2[e * D_IN + cg + 64 * m];
#pragma unroll
    for (int i = 0; i < 4; ++i) {
        const int r = rg2 * 4 + i;
        const float cw = cwS[r];
        float* op = out + (size_t)tokS[r] * D_IN + cg;
#pragma unroll
        for (int m = 0; m < 8; ++m)
            atomicAdd(op + 64 * m, (acc[i][m] + b2v[m]) * cw);
    }
}

// ---------------------------------------------------------------------------
extern "C" void kernel_launch(void* const* d_in, const int* in_sizes, int n_in,
                              void* d_out, int out_size, void* d_ws, size_t ws_size,
                              hipStream_t stream) {
    const float* x  = (const float*)d_in[0];
    const float* Wg = (const float*)d_in[1];
    const float* bg = (const float*)d_in[2];
    const float* W1 = (const float*)d_in[3];
    const float* b1 = (const float*)d_in[4];
    const float* W2 = (const float*)d_in[5];
    const float* b2 = (const float*)d_in[6];

    float* out   = (float*)d_out;
    float* gates = out + (size_t)N_TOK * D_IN;

    // ws layout: counts | recE | recG | lists | cw | xb | w1t | w2t | slot | y
    const size_t o_recE  = 1024;
    const size_t o_recG  = o_recE + (size_t)N_TOK * 8;
    const size_t o_lists = o_recG + (size_t)N_TOK * 8;
    const size_t o_cw    = o_lists + (size_t)N_EXP * N_TOK * 4;
    const size_t o_xb    = o_cw + (size_t)N_EXP * N_TOK * 4;
    const size_t o_w1t   = o_xb + (size_t)N_TOK * D_IN * 2;
    const size_t o_w2t   = o_w1t + (size_t)N_EXP * D_IN * H_DIM * 2;
    const size_t o_slot  = o_w2t + (size_t)N_EXP * D_IN * H_DIM * 2;
    const size_t o_y     = o_slot + (size_t)N_TOK * 2 * 4;
    const size_t NEED1   = o_slot;                                   // ~38.1 MB
    const size_t NEED2   = o_y + (size_t)N_EXP * YROWS * D_IN * 4;   // ~56.4 MB

    int*    counts  = (int*)d_ws;
    int2*   recE    = (int2*)((char*)d_ws + o_recE);
    float2* recG    = (float2*)((char*)d_ws + o_recG);
    int*    lists   = (int*)((char*)d_ws + o_lists);
    float*  cwA     = (float*)((char*)d_ws + o_cw);
    u16*    xb      = (u16*)((char*)d_ws + o_xb);
    u16*    w1t    = (u16*)((char*)d_ws + o_w1t);
    u16*    w2t    = (u16*)((char*)d_ws + o_w2t);
    int*    slotRec = (int*)((char*)d_ws + o_slot);
    float*  yws     = (float*)((char*)d_ws + o_y);

    const int mode = (ws_size >= NEED2) ? 2 : (ws_size >= NEED1 ? 1 : 0);
    const int nconv = (mode >= 1) ? 4096 : 0;
    const int nprep = nconv + N_TOK / 4;      // gate: 4 tokens/block, 4 waves

    moe_prep<<<nprep, 256, 0, stream>>>(
        W1, W2, w1t, w2t, nconv,
        x, Wg, bg, gates, recE, recG, xb, mode >= 1 ? 1 : 0, counts);
    build_lists<<<64, 256, 0, stream>>>(recE, recG, counts, lists, cwA,
                                        mode == 2 ? slotRec : (int*)nullptr);

    if (mode == 2) {
        moe_expert_mfma3<<<N_EXP * MAXT, 256, 0, stream>>>(
            xb, w1t, w2t, b1, b2, yws, counts, lists, cwA);
        moe_combine<<<N_TOK / 2, 256, 0, stream>>>(yws, slotRec, recE, out);
    } else if (mode == 1) {
        hipMemsetAsync(d_out, 0, (size_t)N_TOK * D_IN * sizeof(float), stream);
        moe_expert_mfma<<<N_EXP * MAXT * 8, 256, 0, stream>>>(
            xb, w1t, w2t, b1, b2, out, counts, lists, cwA);
    } else {
        hipMemsetAsync(d_out, 0, (size_t)N_TOK * D_IN * sizeof(float), stream);
        moe_expert_fp32<<<N_EXP * 256, 256, 0, stream>>>(
            x, W1, b1, W2, b2, out, counts, lists, cwA);
    }
}

// Round 5
// 284.551 us; speedup vs baseline: 1.2535x; 1.2535x over previous
//
#include <hip/hip_runtime.h>
#include <math.h>
#include <stdint.h>

// MoE: E=8, top-2, D=512, H=2048, N=4096, fp32 in/out.
// Round 10 (resubmit; r10 bench was an infra failure, kernel unchanged):
//   H-split=2 for 2 co-resident blocks/CU (cross-block TLP).
//   r9 post-mortem: direct-VGPR B regressed (234us, MfmaUtil 5.8%, VALU 2.9%)
//   -- 1 block/CU = 1 wave/SIMD = zero latency hiding. r7/r8's real limit was
//   the same: ~256 real blocks on 256 CUs. Fix: split each expert's H=2048
//   into 2 half-blocks (hs=0: si 0..3, hs=1: si 4..7) -> 512 real blocks ->
//   2 blocks/CU (LDS 71KB fits exactly 2). While one block drains its staging
//   at a barrier, the other block's waves issue MFMA (m114 overlap).
//   y gets SPLIT partials per (token,expert), combine sums 2*SPLIT rows --
//   still zero atomics. SPLIT templated; SPLIT=1 = known-good r8 kernel as
//   workspace fallback (y for SPLIT=2 needs ~80MB ws).

#define N_TOK 4096
#define D_IN  512
#define H_DIM 2048
#define N_EXP 8
#define TM    32
#define HS    256
#define MAXT  40                // covers cnt up to 1280 (expected ~1024)
#define YROWS (MAXT * TM)       // 1280 y slots per expert
#define HROW  264               // u16 stride: 528B rows, 16B-aligned

typedef float  f32x4  __attribute__((ext_vector_type(4)));
typedef short  short8 __attribute__((ext_vector_type(8)));
typedef unsigned short u16;

__device__ __forceinline__ u16 bf16_rne(float f) {
    uint32_t u = __float_as_uint(f);
    return (u16)((u + 0x7fffu + ((u >> 16) & 1u)) >> 16);
}
__device__ __forceinline__ void async16(const u16* g, u16* l) {
    __builtin_amdgcn_global_load_lds(
        (const __attribute__((address_space(1))) void*)g,
        (__attribute__((address_space(3))) void*)l, 16, 0, 0);
}

// ---------------------------------------------------------------------------
// Gate body: one wave per token.
// ---------------------------------------------------------------------------
__device__ __forceinline__ void gate_one(
    int n, int l,
    const float* __restrict__ x, const float* __restrict__ Wg,
    const float* __restrict__ bg, float* __restrict__ gates,
    int2* __restrict__ recE, float2* __restrict__ recG,
    u16* __restrict__ xb, int write_xb)
{
    const float* xr  = x + (size_t)n * D_IN + l * 8;
    const float* wgr = Wg + (size_t)l * 8 * N_EXP;

    float xv[8];
    *(float4*)&xv[0] = *(const float4*)xr;
    *(float4*)&xv[4] = *(const float4*)(xr + 4);

    if (write_xb) {
        short8 pk;
#pragma unroll
        for (int i = 0; i < 8; ++i) pk[i] = (short)bf16_rne(xv[i]);
        *(short8*)(xb + (size_t)n * D_IN + l * 8) = pk;
    }

    float acc[8] = {0.f, 0.f, 0.f, 0.f, 0.f, 0.f, 0.f, 0.f};
#pragma unroll
    for (int dd = 0; dd < 8; ++dd) {
        float4 wa = *(const float4*)(wgr + dd * N_EXP);
        float4 wb = *(const float4*)(wgr + dd * N_EXP + 4);
        acc[0] = fmaf(xv[dd], wa.x, acc[0]);
        acc[1] = fmaf(xv[dd], wa.y, acc[1]);
        acc[2] = fmaf(xv[dd], wa.z, acc[2]);
        acc[3] = fmaf(xv[dd], wa.w, acc[3]);
        acc[4] = fmaf(xv[dd], wb.x, acc[4]);
        acc[5] = fmaf(xv[dd], wb.y, acc[5]);
        acc[6] = fmaf(xv[dd], wb.z, acc[6]);
        acc[7] = fmaf(xv[dd], wb.w, acc[7]);
    }
#pragma unroll
    for (int off = 32; off >= 1; off >>= 1) {
#pragma unroll
        for (int e = 0; e < N_EXP; ++e)
            acc[e] += __shfl_xor(acc[e], off);
    }

    float g[8];
    float mx = -3.4e38f;
#pragma unroll
    for (int e = 0; e < N_EXP; ++e) { g[e] = acc[e] + bg[e]; mx = fmaxf(mx, g[e]); }
    float s = 0.f;
#pragma unroll
    for (int e = 0; e < N_EXP; ++e) { g[e] = expf(g[e] - mx); s += g[e]; }
    const float inv = 1.0f / s;
#pragma unroll
    for (int e = 0; e < N_EXP; ++e) g[e] *= inv;

    if (l == 0) {
        float* go = gates + (size_t)n * N_EXP;
        *(float4*)go       = make_float4(g[0], g[1], g[2], g[3]);
        *(float4*)(go + 4) = make_float4(g[4], g[5], g[6], g[7]);

        int e1 = 0; float g1 = g[0];
#pragma unroll
        for (int e = 1; e < N_EXP; ++e) if (g[e] > g1) { g1 = g[e]; e1 = e; }
        int e2 = -1; float g2 = -1.f;
#pragma unroll
        for (int e = 0; e < N_EXP; ++e) if (e != e1 && g[e] > g2) { g2 = g[e]; e2 = e; }

        recE[n] = make_int2(e1, e2);
        recG[n] = make_float2(g1, g2);
    }
}

// ---------------------------------------------------------------------------
// Prep: fused transpose-to-bf16 (blocks < nconv) + gating (blocks >= nconv).
// First gate block also zeroes counts.
// ---------------------------------------------------------------------------
__global__ __launch_bounds__(256) void moe_prep(
    const float* __restrict__ W1, const float* __restrict__ W2,
    u16* __restrict__ w1t, u16* __restrict__ w2t, int nconv,
    const float* __restrict__ x, const float* __restrict__ Wg,
    const float* __restrict__ bg, float* __restrict__ gates,
    int2* __restrict__ recE, float2* __restrict__ recG,
    u16* __restrict__ xb, int write_xb, int* __restrict__ counts)
{
    __shared__ u16 th[64][65];
    const int idx = blockIdx.x;
    if (idx < nconv) {
        const int z  = idx >> 8;            // 0..15
        const int e  = z & 7;
        const bool isW2 = z >= 8;
        const float* in = isW2 ? W2 : W1;
        u16* ob         = isW2 ? w2t : w1t;
        const int R = isW2 ? H_DIM : D_IN;
        const int C = isW2 ? D_IN : H_DIM;
        const size_t base = (size_t)e * R * C;
        const int rem = idx & 255;
        const int bx = rem & 31, by = rem >> 5;
        const int c0 = (isW2 ? by : bx) * 64;
        const int r0 = (isW2 ? bx : by) * 64;
        const int c  = threadIdx.x & 63, rq = threadIdx.x >> 6;

#pragma unroll
        for (int i = 0; i < 16; ++i) {
            int r = rq * 16 + i;
            th[r][c] = bf16_rne(in[base + (size_t)(r0 + r) * C + c0 + c]);
        }
        __syncthreads();
#pragma unroll
        for (int i = 0; i < 16; ++i) {
            int rw = rq * 16 + i;
            ob[base + (size_t)(c0 + rw) * R + r0 + c] = th[c][rw];
        }
    } else {
        const int g = idx - nconv;
        if (g == 0 && threadIdx.x < N_EXP) counts[threadIdx.x] = 0;
        const int n = g * 4 + (threadIdx.x >> 6);
        const int l = threadIdx.x & 63;
        gate_one(n, l, x, Wg, bg, gates, recE, recG, xb, write_xb);
    }
}

// ---------------------------------------------------------------------------
// List build: 64 blocks (expert e = bid>>3, 512-token chunk).
// ---------------------------------------------------------------------------
__global__ __launch_bounds__(256) void build_lists(
    const int2* __restrict__ recE, const float2* __restrict__ recG,
    int* __restrict__ counts, int* __restrict__ lists, float* __restrict__ cwA,
    int* __restrict__ slotRec)
{
    __shared__ int cnt, base;
    __shared__ int   ltok[512];
    __shared__ float lcw[512];
    __shared__ int   lsrc[512];
    const int e  = blockIdx.x >> 3;
    const int c0 = (blockIdx.x & 7) * 512;
    const int tid = threadIdx.x;
    if (tid == 0) cnt = 0;
    __syncthreads();
#pragma unroll
    for (int it = 0; it < 2; ++it) {
        int t = c0 + it * 256 + tid;
        int2   ee = recE[t];
        float2 gg = recG[t];
        if (ee.x == e) {
            int p = atomicAdd(&cnt, 1);
            ltok[p] = t;  lcw[p] = gg.x;  lsrc[p] = 2 * t;
        }
        if (ee.y == e) {
            int p = atomicAdd(&cnt, 1);
            ltok[p] = t;  lcw[p] = gg.y;  lsrc[p] = 2 * t + 1;
        }
    }
    __syncthreads();
    if (tid == 0) base = atomicAdd(&counts[e], cnt);
    __syncthreads();
    const int c = cnt, b0 = base;
    for (int i = tid; i < c; i += 256) {
        int p = b0 + i;
        lists[e * N_TOK + p] = ltok[i];
        cwA[e * N_TOK + p]   = lcw[i];
        if (slotRec) slotRec[lsrc[i]] = p;
    }
}

// ---------------------------------------------------------------------------
// Expert kernel (r8 pipeline, templated H-split).
//   SPLIT=1: full H per block, grid 8*MAXT (known-good r8).
//   SPLIT=2: half H per block (hs picks si 0..3 / 4..7), grid 8*2*MAXT =
//            512 real blocks -> 2 blocks/CU -> cross-block latency hiding.
//   Per si: G1 16 steps (counted vmcnt, triple-buffer 16KB chunks) -> hT ->
//   G2 16 steps. accY[4][2][2] persistent; dense y partial stores (hs adds
//   b2 only at hs==0); zero atomics.
// LDS: sB 48KB + sA 6KB + hT 16.5KB = ~71KB -> exactly 2 blocks/CU.
// ---------------------------------------------------------------------------
#define STG1(si_, ks_, buf_)                                                  \
    do {                                                                      \
        const u16* _s = w1E + (size_t)(si_) * (HS * D_IN) + (ks_) * 32;       \
        _Pragma("unroll")                                                     \
        for (int _i = 0; _i < 4; ++_i)                                        \
            async16(_s + bOffB[_i], &sB[buf_][dstB + _i * 512]);              \
        if (w < 2)                                                            \
            async16(xb + aOffW + (ks_) * 32, &sA[buf_][w * 512 + lane * 8]);  \
    } while (0)

#define STG2(si_, u2_, buf_)                                                  \
    do {                                                                      \
        const int _nc = (u2_) >> 2, _k2 = (u2_) & 3;                          \
        const u16* _s = w2E + (size_t)_nc * (128 * H_DIM) + (si_) * HS + _k2 * 64; \
        _Pragma("unroll")                                                     \
        for (int _i = 0; _i < 4; ++_i)                                        \
            async16(_s + bOff2[_i], &sB[buf_][dstB + _i * 512]);              \
    } while (0)

#define BARX do { __builtin_amdgcn_s_barrier();                               \
                  __builtin_amdgcn_sched_barrier(0); } while (0)

template <int SPLIT>
__global__ __launch_bounds__(256, 2) void moe_expert_mfma2(
    const u16* __restrict__ xb,
    const u16* __restrict__ w1t, const u16* __restrict__ w2t,
    const float* __restrict__ b1, const float* __restrict__ b2,
    float* __restrict__ y,
    const int* __restrict__ counts, const int* __restrict__ lists,
    const float* __restrict__ cwA)
{
    const int b  = blockIdx.x;
    const int e  = b & 7;            // expert -> XCD affinity
    const int q  = b >> 3;
    const int hs = q & (SPLIT - 1);  // H half
    const int t  = q / SPLIT;
    int cnt = counts[e];
    if (cnt > YROWS) cnt = YROWS;
    if (t * TM >= cnt) return;

    __shared__ __align__(16) u16 sB[3][8192];    // 48 KB: 3x16KB chunks
    __shared__ __align__(16) u16 sA[3][1024];    //  6 KB: 3x2KB x chunks
    __shared__ __align__(16) u16 hT[TM * HROW];  // 16.5 KB
    __shared__ int   tokS[TM];
    __shared__ float cwS[TM];

    const int tid  = threadIdx.x;
    const int w    = tid >> 6;
    const int lane = tid & 63;
    const int quad = lane >> 4;
    const int l16  = lane & 15;

    if (tid < TM) {
        int gi = t * TM + tid;
        bool v = gi < cnt;
        tokS[tid] = v ? lists[e * N_TOK + gi] : 0;
        cwS[tid]  = v ? cwA[e * N_TOK + gi] : 0.f;   // cw=0 kills pad rows
    }
    __syncthreads();

    // ---- staging geometry (lds dest = wave base + lane*16B) ----
    const int r4   = lane >> 2;                       // G1: 16 rows/inst
    const int csw1 = (lane & 3) ^ ((lane >> 4) & 3);  // key=(rowInChunk>>2)&3
    const int r8   = lane >> 3;                       // G2: 8 rows/inst
    const int csw2 = (lane & 7) ^ r8;                 // key=rowInChunk&7
    const int dstB = w * 2048 + lane * 8;             // u16 offset in sB buf

    // ---- fragment read offsets (u16 elements, within a buffer) ----
    int fB1[4], fA1[2];
#pragma unroll
    for (int nt = 0; nt < 4; ++nt) {
        int r = w * 64 + nt * 16 + l16;
        fB1[nt] = r * 32 + (quad ^ ((l16 >> 2) & 3)) * 8;
    }
#pragma unroll
    for (int m = 0; m < 2; ++m) {
        int r = m * 16 + l16;
        fA1[m] = r * 32 + (quad ^ ((l16 >> 2) & 3)) * 8;
    }
    int fB2[2][2], fA2[2];
#pragma unroll
    for (int nt = 0; nt < 2; ++nt)
#pragma unroll
        for (int kk = 0; kk < 2; ++kk) {
            int r = w * 32 + nt * 16 + l16;
            fB2[nt][kk] = r * 64 + (((kk * 4 + quad) ^ (l16 & 7)) * 8);
        }
#pragma unroll
    for (int m = 0; m < 2; ++m)
        fA2[m] = (m * 16 + l16) * HROW + quad * 8;

    // ---- global staging offsets ----
    const u16* w1E = w1t + (size_t)e * H_DIM * D_IN;
    const u16* w2E = w2t + (size_t)e * D_IN * H_DIM;
    int bOffB[4];
#pragma unroll
    for (int i = 0; i < 4; ++i)
        bOffB[i] = (w * 64 + i * 16 + r4) * D_IN + csw1 * 8;
    int bOff2[4];
#pragma unroll
    for (int i = 0; i < 4; ++i)
        bOff2[i] = (w * 32 + i * 8 + r8) * H_DIM + csw2 * 8;
    int aOffW = 0;
    if (w < 2) aOffW = tokS[w * 16 + r4] * D_IN + csw1 * 8;

    // ---- persistent output accumulator: y[32][512] over this H range ----
    f32x4 accY[4][2][2];
#pragma unroll
    for (int nc = 0; nc < 4; ++nc)
#pragma unroll
        for (int m = 0; m < 2; ++m)
#pragma unroll
            for (int nt = 0; nt < 2; ++nt)
                accY[nc][m][nt] = (f32x4){0.f, 0.f, 0.f, 0.f};

    const int NSI = 8 / SPLIT;
    for (int sq = 0; sq < NSI; ++sq) {
        const int si = hs * NSI + sq;
        // bias slice loads early (oldest vmem -> drained by u=0 wait)
        float b1v[4];
#pragma unroll
        for (int nt = 0; nt < 4; ++nt)
            b1v[nt] = b1[e * H_DIM + si * HS + w * 64 + nt * 16 + l16];

        // per-si pipeline refill
        STG1(si, 0, 0);

        // -------- GEMM1: h[32][256] = xb-tile @ W1T-slice(si) --------
        f32x4 acc1[2][4];
#pragma unroll
        for (int m = 0; m < 2; ++m)
#pragma unroll
            for (int nt = 0; nt < 4; ++nt) acc1[m][nt] = (f32x4){0.f, 0.f, 0.f, 0.f};

#pragma unroll
        for (int u = 0; u < 16; ++u) {
            if (u == 0) {
                asm volatile("s_waitcnt vmcnt(0)" ::: "memory");
            } else if (u < 15) {
                if (w < 2) asm volatile("s_waitcnt vmcnt(5)" ::: "memory");
                else       asm volatile("s_waitcnt vmcnt(4)" ::: "memory");
            } else {
                asm volatile("s_waitcnt vmcnt(4)" ::: "memory");
            }
            BARX;
            if (u == 0)       { STG1(si, 1, 1); STG1(si, 2, 2); }
            else if (u < 14)  { STG1(si, u + 2, (u + 2) % 3); }
            else if (u == 14) { STG2(si, 0, 1); }
            else              { STG2(si, 1, 2); }

            const u16* Bp = &sB[u % 3][0];
            const u16* Ap = &sA[u % 3][0];
            short8 bf[4], af[2];
#pragma unroll
            for (int nt = 0; nt < 4; ++nt) bf[nt] = *(const short8*)(Bp + fB1[nt]);
#pragma unroll
            for (int m = 0; m < 2; ++m)  af[m] = *(const short8*)(Ap + fA1[m]);
            __builtin_amdgcn_s_setprio(1);
#pragma unroll
            for (int nt = 0; nt < 4; ++nt)
#pragma unroll
                for (int m = 0; m < 2; ++m)
                    acc1[m][nt] = __builtin_amdgcn_mfma_f32_16x16x32_bf16(
                        af[m], bf[nt], acc1[m][nt], 0, 0, 0);
            __builtin_amdgcn_s_setprio(0);
        }

        // -------- epilogue 1: bias + relu -> hT (bf16) --------
#pragma unroll
        for (int nt = 0; nt < 4; ++nt) {
            const int c = w * 64 + nt * 16 + l16;
#pragma unroll
            for (int m = 0; m < 2; ++m)
#pragma unroll
                for (int r = 0; r < 4; ++r) {
                    int row = m * 16 + quad * 4 + r;
                    hT[row * HROW + c] = bf16_rne(fmaxf(acc1[m][nt][r] + b1v[nt], 0.f));
                }
        }

        // -------- GEMM2: accY += hT @ W2T-slice(si) --------
#pragma unroll
        for (int u = 0; u < 16; ++u) {
            if (u == 0)      asm volatile("s_waitcnt vmcnt(4) lgkmcnt(0)" ::: "memory");
            else if (u < 15) asm volatile("s_waitcnt vmcnt(4)" ::: "memory");
            else             asm volatile("s_waitcnt vmcnt(0)" ::: "memory");
            BARX;
            if (u < 14) STG2(si, u + 2, u % 3);

            const int nc = u >> 2, k2 = u & 3;
            const u16* Bp = &sB[(u + 1) % 3][0];
#pragma unroll
            for (int kk = 0; kk < 2; ++kk) {
                short8 a0  = *(const short8*)(hT + fA2[0] + k2 * 64 + kk * 32);
                short8 a1  = *(const short8*)(hT + fA2[1] + k2 * 64 + kk * 32);
                short8 b0  = *(const short8*)(Bp + fB2[0][kk]);
                short8 b1f = *(const short8*)(Bp + fB2[1][kk]);
                __builtin_amdgcn_s_setprio(1);
                accY[nc][0][0] = __builtin_amdgcn_mfma_f32_16x16x32_bf16(a0, b0,  accY[nc][0][0], 0, 0, 0);
                accY[nc][1][0] = __builtin_amdgcn_mfma_f32_16x16x32_bf16(a1, b0,  accY[nc][1][0], 0, 0, 0);
                accY[nc][0][1] = __builtin_amdgcn_mfma_f32_16x16x32_bf16(a0, b1f, accY[nc][0][1], 0, 0, 0);
                accY[nc][1][1] = __builtin_amdgcn_mfma_f32_16x16x32_bf16(a1, b1f, accY[nc][1][1], 0, 0, 0);
                __builtin_amdgcn_s_setprio(0);
            }
        }
    }

    // -------- epilogue: dense y partial write: (acc [+b2 at hs0]) * cw ----
    float* yT = y + (((size_t)e * SPLIT + hs) * YROWS + (size_t)t * TM) * D_IN;
#pragma unroll
    for (int nc = 0; nc < 4; ++nc)
#pragma unroll
        for (int nt = 0; nt < 2; ++nt) {
            const int dcol = nc * 128 + w * 32 + nt * 16 + l16;
            const float bias = (hs == 0) ? b2[e * D_IN + dcol] : 0.f;
#pragma unroll
            for (int m = 0; m < 2; ++m)
#pragma unroll
                for (int r = 0; r < 4; ++r) {
                    const int row = m * 16 + quad * 4 + r;
                    yT[(size_t)row * D_IN + dcol] =
                        (accY[nc][m][nt][r] + bias) * cwS[row];
                }
        }
}

// ---------------------------------------------------------------------------
// Combine: out[t] = sum over k in {1,2}, hs in 0..SPLIT-1 of y partials.
// ---------------------------------------------------------------------------
template <int SPLIT>
__global__ __launch_bounds__(256) void moe_combine(
    const float* __restrict__ y, const int* __restrict__ slotRec,
    const int2* __restrict__ recE, float* __restrict__ out)
{
    const int t  = blockIdx.x * 2 + (threadIdx.x >> 7);
    const int c4 = (threadIdx.x & 127) << 2;
    const int2 ee = recE[t];
    int s1 = slotRec[2 * t + 0];
    int s2 = slotRec[2 * t + 1];
    s1 = s1 < YROWS ? s1 : YROWS - 1;   // safety clamp
    s2 = s2 < YROWS ? s2 : YROWS - 1;
    float4 acc = make_float4(0.f, 0.f, 0.f, 0.f);
#pragma unroll
    for (int h = 0; h < SPLIT; ++h) {
        const float4 a = *(const float4*)(
            y + (((size_t)ee.x * SPLIT + h) * YROWS + s1) * D_IN + c4);
        const float4 bb = *(const float4*)(
            y + (((size_t)ee.y * SPLIT + h) * YROWS + s2) * D_IN + c4);
        acc.x += a.x + bb.x;  acc.y += a.y + bb.y;
        acc.z += a.z + bb.z;  acc.w += a.w + bb.w;
    }
    *(float4*)(out + (size_t)t * D_IN + c4) = acc;
}

// ---------------------------------------------------------------------------
// r6 single-pass bf16 expert kernel (known-passing) — fallback if ws small.
// ---------------------------------------------------------------------------
__global__ __launch_bounds__(256, 4) void moe_expert_mfma(
    const u16* __restrict__ xb,
    const u16* __restrict__ w1t, const u16* __restrict__ w2t,
    const float* __restrict__ b1, const float* __restrict__ b2,
    float* __restrict__ out,
    const int* __restrict__ counts, const int* __restrict__ lists,
    const float* __restrict__ cwA)
{
    const int b = blockIdx.x;
    const int s = b & 7;
    const int q = b >> 3;
    const int t = q % MAXT;
    const int e = q / MAXT;
    const int cnt = counts[e];
    if (t * TM >= cnt) return;

    __shared__ __align__(16) u16 sB[8192];
    __shared__ __align__(16) u16 sA[1024];
    __shared__ __align__(16) u16 hT[TM * HROW];
    __shared__ int   tokS[TM];
    __shared__ float cwS[TM];

    const int tid  = threadIdx.x;
    const int w    = tid >> 6;
    const int lane = tid & 63;
    const int quad = lane >> 4;
    const int l16  = lane & 15;

    if (tid < TM) {
        int gi = t * TM + tid;
        bool v = gi < cnt;
        tokS[tid] = v ? lists[e * N_TOK + gi] : 0;
        cwS[tid]  = v ? cwA[e * N_TOK + gi] : 0.f;
    }
    __syncthreads();

    const int r4   = lane >> 2;
    const int csw1 = (lane & 3) ^ ((lane >> 4) & 3);
    const int r8   = lane >> 3;
    const int csw2 = (lane & 7) ^ r8;
    u16* ldsB0 = sB + w * 2048 + lane * 8;
    u16* ldsA0 = sA + lane * 8;

    int fB1[4], fA1[2];
#pragma unroll
    for (int nt = 0; nt < 4; ++nt) {
        int r = w * 64 + nt * 16 + l16;
        fB1[nt] = r * 32 + (quad ^ ((l16 >> 2) & 3)) * 8;
    }
#pragma unroll
    for (int m = 0; m < 2; ++m) {
        int r = m * 16 + l16;
        fA1[m] = r * 32 + (quad ^ ((l16 >> 2) & 3)) * 8;
    }
    int fB2[2][2], fA2[2];
#pragma unroll
    for (int nt = 0; nt < 2; ++nt)
#pragma unroll
        for (int kk = 0; kk < 2; ++kk) {
            int r = w * 32 + nt * 16 + l16;
            fB2[nt][kk] = r * 64 + (((kk * 4 + quad) ^ (l16 & 7)) * 8);
        }
#pragma unroll
    for (int m = 0; m < 2; ++m)
        fA2[m] = (m * 16 + l16) * HROW + quad * 8;

    int bOffB[4];
#pragma unroll
    for (int i = 0; i < 4; ++i)
        bOffB[i] = (s * HS + w * 64 + i * 16 + r4) * D_IN + csw1 * 8;
    int aOff0 = tokS[r4]      * D_IN + csw1 * 8;
    int aOff1 = tokS[16 + r4] * D_IN + csw1 * 8;
    const u16* w1E = w1t + (size_t)e * H_DIM * D_IN;

    f32x4 acc1[2][4];
#pragma unroll
    for (int m = 0; m < 2; ++m)
#pragma unroll
        for (int nt = 0; nt < 4; ++nt) acc1[m][nt] = (f32x4){0.f, 0.f, 0.f, 0.f};

    for (int ks = 0; ks < 16; ++ks) {
        const int kb = ks * 32;
        __syncthreads();
#pragma unroll
        for (int i = 0; i < 4; ++i)
            async16(w1E + bOffB[i] + kb, ldsB0 + i * 512);
        if (w == 0) {
            async16(xb + aOff0 + kb, ldsA0);
            async16(xb + aOff1 + kb, ldsA0 + 512);
        }
        __syncthreads();
        short8 bf[4], af[2];
#pragma unroll
        for (int nt = 0; nt < 4; ++nt) bf[nt] = *(const short8*)(sB + fB1[nt]);
#pragma unroll
        for (int m = 0; m < 2; ++m)  af[m] = *(const short8*)(sA + fA1[m]);
#pragma unroll
        for (int nt = 0; nt < 4; ++nt)
#pragma unroll
            for (int m = 0; m < 2; ++m)
                acc1[m][nt] = __builtin_amdgcn_mfma_f32_16x16x32_bf16(af[m], bf[nt], acc1[m][nt], 0, 0, 0);
    }

#pragma unroll
    for (int nt = 0; nt < 4; ++nt) {
        const int c = w * 64 + nt * 16 + l16;
        const float bias = b1[e * H_DIM + s * HS + c];
#pragma unroll
        for (int m = 0; m < 2; ++m)
#pragma unroll
            for (int r = 0; r < 4; ++r) {
                int row = m * 16 + quad * 4 + r;
                hT[row * HROW + c] = bf16_rne(fmaxf(acc1[m][nt][r] + bias, 0.f));
            }
    }

    const u16* w2E = w2t + (size_t)e * D_IN * H_DIM;
    int bOff2[4];
#pragma unroll
    for (int i = 0; i < 4; ++i)
        bOff2[i] = (w * 32 + i * 8 + r8) * H_DIM + s * HS + csw2 * 8;

    for (int nc = 0; nc < 4; ++nc) {
        f32x4 acc2[2][2];
#pragma unroll
        for (int m = 0; m < 2; ++m)
#pragma unroll
            for (int nt = 0; nt < 2; ++nt) acc2[m][nt] = (f32x4){0.f, 0.f, 0.f, 0.f};

        for (int ks = 0; ks < 4; ++ks) {
            __syncthreads();
#pragma unroll
            for (int i = 0; i < 4; ++i)
                async16(w2E + bOff2[i] + nc * (128 * H_DIM) + ks * 64,
                        ldsB0 + i * 512);
            __syncthreads();
#pragma unroll
            for (int kk = 0; kk < 2; ++kk) {
                short8 a0  = *(const short8*)(hT + fA2[0] + ks * 64 + kk * 32);
                short8 a1  = *(const short8*)(hT + fA2[1] + ks * 64 + kk * 32);
                short8 b0  = *(const short8*)(sB + fB2[0][kk]);
                short8 b1f = *(const short8*)(sB + fB2[1][kk]);
                acc2[0][0] = __builtin_amdgcn_mfma_f32_16x16x32_bf16(a0, b0,  acc2[0][0], 0, 0, 0);
                acc2[1][0] = __builtin_amdgcn_mfma_f32_16x16x32_bf16(a1, b0,  acc2[1][0], 0, 0, 0);
                acc2[0][1] = __builtin_amdgcn_mfma_f32_16x16x32_bf16(a0, b1f, acc2[0][1], 0, 0, 0);
                acc2[1][1] = __builtin_amdgcn_mfma_f32_16x16x32_bf16(a1, b1f, acc2[1][1], 0, 0, 0);
            }
        }

#pragma unroll
        for (int nt = 0; nt < 2; ++nt) {
            const int dcol = nc * 128 + w * 32 + nt * 16 + l16;
            const float bias = (s == 0) ? b2[e * D_IN + dcol] : 0.f;
#pragma unroll
            for (int m = 0; m < 2; ++m)
#pragma unroll
                for (int r = 0; r < 4; ++r) {
                    int row = m * 16 + quad * 4 + r;
                    float v = (acc2[m][nt][r] + bias) * cwS[row];
                    atomicAdd(out + (size_t)tokS[row] * D_IN + dcol, v);
                }
        }
    }
}

// ---------------------------------------------------------------------------
// Fallback fp32 expert kernel (round 1, known-passing) — used if ws tiny.
// ---------------------------------------------------------------------------
__global__ __launch_bounds__(256, 4) void moe_expert_fp32(
    const float* __restrict__ x,  const float* __restrict__ W1,
    const float* __restrict__ b1, const float* __restrict__ W2,
    const float* __restrict__ b2, float* __restrict__ out,
    const int* __restrict__ counts, const int* __restrict__ lists,
    const float* __restrict__ cwA)
{
    const int e    = blockIdx.x & 7;
    const int tile = blockIdx.x >> 3;
    const int cnt  = counts[e];
    if (tile * 16 >= cnt) return;

    __shared__ float xs[16 * 520];
    __shared__ float hs[16 * 68];
    __shared__ int   tokS[16];
    __shared__ float cwS[16];

    const int tid = threadIdx.x;
    if (tid < 16) {
        int gi = tile * 16 + tid;
        bool v = gi < cnt;
        tokS[tid] = v ? lists[e * N_TOK + gi] : 0;
        cwS[tid]  = v ? cwA[e * N_TOK + gi]  : 0.f;
    }
    __syncthreads();
    {
        const int i = tid >> 4, p = tid & 15;
        const float* xr = x + (size_t)tokS[i] * D_IN + p * 32;
        float* xd = xs + i * 520 + p * 32;
#pragma unroll
        for (int qq = 0; qq < 8; ++qq)
            *(float4*)(xd + qq * 4) = *(const float4*)(xr + qq * 4);
    }
    __syncthreads();

    const float* W1e = W1 + (size_t)e * D_IN * H_DIM;
    const float* W2e = W2 + (size_t)e * H_DIM * D_IN;
    const int j = tid & 31, rg1 = tid >> 5, cg = tid & 63, rg2 = tid >> 6;

    float acc[4][8];
#pragma unroll
    for (int i = 0; i < 4; ++i)
#pragma unroll
        for (int m = 0; m < 8; ++m) acc[i][m] = 0.f;

    for (int hc = 0; hc < H_DIM / 64; ++hc) {
        float a1[2][2] = {{0.f, 0.f}, {0.f, 0.f}};
        const float* w1p = W1e + hc * 64 + j;
        for (int d = 0; d < D_IN; d += 4) {
            float xv[2][4];
            *(float4*)xv[0] = *(const float4*)(xs + (rg1 * 2 + 0) * 520 + d);
            *(float4*)xv[1] = *(const float4*)(xs + (rg1 * 2 + 1) * 520 + d);
#pragma unroll
            for (int dd = 0; dd < 4; ++dd) {
                float wa = w1p[(size_t)(d + dd) * H_DIM];
                float wb = w1p[(size_t)(d + dd) * H_DIM + 32];
                a1[0][0] = fmaf(xv[0][dd], wa, a1[0][0]);
                a1[0][1] = fmaf(xv[0][dd], wb, a1[0][1]);
                a1[1][0] = fmaf(xv[1][dd], wa, a1[1][0]);
                a1[1][1] = fmaf(xv[1][dd], wb, a1[1][1]);
            }
        }
        float b1a = b1[e * H_DIM + hc * 64 + j];
        float b1b = b1[e * H_DIM + hc * 64 + j + 32];
        __syncthreads();
        hs[(rg1 * 2 + 0) * 68 + j]      = fmaxf(a1[0][0] + b1a, 0.f);
        hs[(rg1 * 2 + 0) * 68 + j + 32] = fmaxf(a1[0][1] + b1b, 0.f);
        hs[(rg1 * 2 + 1) * 68 + j]      = fmaxf(a1[1][0] + b1a, 0.f);
        hs[(rg1 * 2 + 1) * 68 + j + 32] = fmaxf(a1[1][1] + b1b, 0.f);
        __syncthreads();
        const float* w2p = W2e + (size_t)(hc * 64) * D_IN + cg;
        for (int k = 0; k < 64; k += 4) {
            float hv[4][4];
#pragma unroll
            for (int i = 0; i < 4; ++i)
                *(float4*)hv[i] = *(const float4*)(hs + (rg2 * 4 + i) * 68 + k);
#pragma unroll
            for (int kk = 0; kk < 4; ++kk) {
                float w2r[8];
#pragma unroll
                for (int m = 0; m < 8; ++m)
                    w2r[m] = w2p[(size_t)(k + kk) * D_IN + 64 * m];
#pragma unroll
                for (int i = 0; i < 4; ++i)
#pragma unroll
                    for (int m = 0; m < 8; ++m)
                        acc[i][m] = fmaf(hv[i][kk], w2r[m], acc[i][m]);
            }
        }
        __syncthreads();
    }
    float b2v[8];
#pragma unroll
    for (int m = 0; m < 8; ++m) b2v[m] = b2[e * D_IN + cg + 64 * m];
#pragma unroll
    for (int i = 0; i < 4; ++i) {
        const int r = rg2 * 4 + i;
        const float cw = cwS[r];
        float* op = out + (size_t)tokS[r] * D_IN + cg;
#pragma unroll
        for (int m = 0; m < 8; ++m)
            atomicAdd(op + 64 * m, (acc[i][m] + b2v[m]) * cw);
    }
}

// ---------------------------------------------------------------------------
extern "C" void kernel_launch(void* const* d_in, const int* in_sizes, int n_in,
                              void* d_out, int out_size, void* d_ws, size_t ws_size,
                              hipStream_t stream) {
    const float* x  = (const float*)d_in[0];
    const float* Wg = (const float*)d_in[1];
    const float* bg = (const float*)d_in[2];
    const float* W1 = (const float*)d_in[3];
    const float* b1 = (const float*)d_in[4];
    const float* W2 = (const float*)d_in[5];
    const float* b2 = (const float*)d_in[6];

    float* out   = (float*)d_out;
    float* gates = out + (size_t)N_TOK * D_IN;

    // ws layout: counts | recE | recG | lists | cw | xb | w1t | w2t | slot | y
    const size_t o_recE  = 1024;
    const size_t o_recG  = o_recE + (size_t)N_TOK * 8;
    const size_t o_lists = o_recG + (size_t)N_TOK * 8;
    const size_t o_cw    = o_lists + (size_t)N_EXP * N_TOK * 4;
    const size_t o_xb    = o_cw + (size_t)N_EXP * N_TOK * 4;
    const size_t o_w1t   = o_xb + (size_t)N_TOK * D_IN * 2;
    const size_t o_w2t   = o_w1t + (size_t)N_EXP * D_IN * H_DIM * 2;
    const size_t o_slot  = o_w2t + (size_t)N_EXP * D_IN * H_DIM * 2;
    const size_t o_y     = o_slot + (size_t)N_TOK * 2 * 4;
    const size_t ybytes1 = (size_t)N_EXP * YROWS * D_IN * 4;         // 21.0 MB
    const size_t NEED1   = o_slot;                                   // ~38.1 MB
    const size_t NEED2   = o_y + ybytes1;                            // ~59.1 MB
    const size_t NEED3   = o_y + 2 * ybytes1;                        // ~80.1 MB

    int*    counts  = (int*)d_ws;
    int2*   recE    = (int2*)((char*)d_ws + o_recE);
    float2* recG    = (float2*)((char*)d_ws + o_recG);
    int*    lists   = (int*)((char*)d_ws + o_lists);
    float*  cwA     = (float*)((char*)d_ws + o_cw);
    u16*    xb      = (u16*)((char*)d_ws + o_xb);
    u16*    w1t    = (u16*)((char*)d_ws + o_w1t);
    u16*    w2t    = (u16*)((char*)d_ws + o_w2t);
    int*    slotRec = (int*)((char*)d_ws + o_slot);
    float*  yws     = (float*)((char*)d_ws + o_y);

    const int mode = (ws_size >= NEED3) ? 3 :
                     (ws_size >= NEED2) ? 2 :
                     (ws_size >= NEED1) ? 1 : 0;
    const int nconv = (mode >= 1) ? 4096 : 0;
    const int nprep = nconv + N_TOK / 4;      // gate: 4 tokens/block, 4 waves

    moe_prep<<<nprep, 256, 0, stream>>>(
        W1, W2, w1t, w2t, nconv,
        x, Wg, bg, gates, recE, recG, xb, mode >= 1 ? 1 : 0, counts);
    build_lists<<<64, 256, 0, stream>>>(recE, recG, counts, lists, cwA,
                                        mode >= 2 ? slotRec : (int*)nullptr);

    if (mode == 3) {
        moe_expert_mfma2<2><<<N_EXP * 2 * MAXT, 256, 0, stream>>>(
            xb, w1t, w2t, b1, b2, yws, counts, lists, cwA);
        moe_combine<2><<<N_TOK / 2, 256, 0, stream>>>(yws, slotRec, recE, out);
    } else if (mode == 2) {
        moe_expert_mfma2<1><<<N_EXP * MAXT, 256, 0, stream>>>(
            xb, w1t, w2t, b1, b2, yws, counts, lists, cwA);
        moe_combine<1><<<N_TOK / 2, 256, 0, stream>>>(yws, slotRec, recE, out);
    } else if (mode == 1) {
        hipMemsetAsync(d_out, 0, (size_t)N_TOK * D_IN * sizeof(float), stream);
        moe_expert_mfma<<<N_EXP * MAXT * 8, 256, 0, stream>>>(
            xb, w1t, w2t, b1, b2, out, counts, lists, cwA);
    } else {
        hipMemsetAsync(d_out, 0, (size_t)N_TOK * D_IN * sizeof(float), stream);
        moe_expert_fp32<<<N_EXP * 256, 256, 0, stream>>>(
            x, W1, b1, W2, b2, out, counts, lists, cwA);
    }
}

// Round 6
// 258.830 us; speedup vs baseline: 1.3781x; 1.0994x over previous
//
#include <hip/hip_runtime.h>
#include <math.h>
#include <stdint.h>

// MoE: E=8, top-2, D=512, H=2048, N=4096, fp32 in/out.
// Round 11: TM=64 (double arithmetic intensity per staged byte).
//   r10 post-mortem: SPLIT=2 co-residency was FLAT (160us) -- steps/CU
//   constant at 256; pace ~1500cy/step unchanged. Lever = per-CU work.
//   v11 expert kernel: 64-token tiles -> staged bytes/CU halve (2.25MB),
//   steps/CU halve (128), MFMA/step doubles (16/wave). Same proven chunk
//   geometry + vmcnt(0)/raw-barrier step machine; dbuf (LDS 73.5KB -> 2
//   blocks/CU); SPLIT=4 (2 si/block) keeps 512 real blocks. y partials
//   bf16 (4 hs x 2 experts summed f32 in combine) so NEED stays 80.05MB.
//   Fallbacks: mode2 = r8 SPLIT=1 f32-y kernel; mode1 = r6; mode0 = fp32.

#define N_TOK 4096
#define D_IN  512
#define H_DIM 2048
#define N_EXP 8
#define TM    32
#define HS    256
#define MAXT  40                // TM=32 tiling (fallback kernels)
#define MAXT64 20               // TM=64 tiling: 20*64 = 1280 slots
#define YROWS (MAXT * TM)       // 1280 y slots per expert
#define HROW  264               // u16 stride: 528B rows, 16B-aligned

typedef float  f32x4  __attribute__((ext_vector_type(4)));
typedef short  short8 __attribute__((ext_vector_type(8)));
typedef short  s16x4  __attribute__((ext_vector_type(4)));
typedef unsigned short u16;

__device__ __forceinline__ u16 bf16_rne(float f) {
    uint32_t u = __float_as_uint(f);
    return (u16)((u + 0x7fffu + ((u >> 16) & 1u)) >> 16);
}
__device__ __forceinline__ float bf16_to_f32(u16 v) {
    return __uint_as_float(((uint32_t)v) << 16);
}
__device__ __forceinline__ void async16(const u16* g, u16* l) {
    __builtin_amdgcn_global_load_lds(
        (const __attribute__((address_space(1))) void*)g,
        (__attribute__((address_space(3))) void*)l, 16, 0, 0);
}

// ---------------------------------------------------------------------------
// Gate body: one wave per token.
// ---------------------------------------------------------------------------
__device__ __forceinline__ void gate_one(
    int n, int l,
    const float* __restrict__ x, const float* __restrict__ Wg,
    const float* __restrict__ bg, float* __restrict__ gates,
    int2* __restrict__ recE, float2* __restrict__ recG,
    u16* __restrict__ xb, int write_xb)
{
    const float* xr  = x + (size_t)n * D_IN + l * 8;
    const float* wgr = Wg + (size_t)l * 8 * N_EXP;

    float xv[8];
    *(float4*)&xv[0] = *(const float4*)xr;
    *(float4*)&xv[4] = *(const float4*)(xr + 4);

    if (write_xb) {
        short8 pk;
#pragma unroll
        for (int i = 0; i < 8; ++i) pk[i] = (short)bf16_rne(xv[i]);
        *(short8*)(xb + (size_t)n * D_IN + l * 8) = pk;
    }

    float acc[8] = {0.f, 0.f, 0.f, 0.f, 0.f, 0.f, 0.f, 0.f};
#pragma unroll
    for (int dd = 0; dd < 8; ++dd) {
        float4 wa = *(const float4*)(wgr + dd * N_EXP);
        float4 wb = *(const float4*)(wgr + dd * N_EXP + 4);
        acc[0] = fmaf(xv[dd], wa.x, acc[0]);
        acc[1] = fmaf(xv[dd], wa.y, acc[1]);
        acc[2] = fmaf(xv[dd], wa.z, acc[2]);
        acc[3] = fmaf(xv[dd], wa.w, acc[3]);
        acc[4] = fmaf(xv[dd], wb.x, acc[4]);
        acc[5] = fmaf(xv[dd], wb.y, acc[5]);
        acc[6] = fmaf(xv[dd], wb.z, acc[6]);
        acc[7] = fmaf(xv[dd], wb.w, acc[7]);
    }
#pragma unroll
    for (int off = 32; off >= 1; off >>= 1) {
#pragma unroll
        for (int e = 0; e < N_EXP; ++e)
            acc[e] += __shfl_xor(acc[e], off);
    }

    float g[8];
    float mx = -3.4e38f;
#pragma unroll
    for (int e = 0; e < N_EXP; ++e) { g[e] = acc[e] + bg[e]; mx = fmaxf(mx, g[e]); }
    float s = 0.f;
#pragma unroll
    for (int e = 0; e < N_EXP; ++e) { g[e] = expf(g[e] - mx); s += g[e]; }
    const float inv = 1.0f / s;
#pragma unroll
    for (int e = 0; e < N_EXP; ++e) g[e] *= inv;

    if (l == 0) {
        float* go = gates + (size_t)n * N_EXP;
        *(float4*)go       = make_float4(g[0], g[1], g[2], g[3]);
        *(float4*)(go + 4) = make_float4(g[4], g[5], g[6], g[7]);

        int e1 = 0; float g1 = g[0];
#pragma unroll
        for (int e = 1; e < N_EXP; ++e) if (g[e] > g1) { g1 = g[e]; e1 = e; }
        int e2 = -1; float g2 = -1.f;
#pragma unroll
        for (int e = 0; e < N_EXP; ++e) if (e != e1 && g[e] > g2) { g2 = g[e]; e2 = e; }

        recE[n] = make_int2(e1, e2);
        recG[n] = make_float2(g1, g2);
    }
}

// ---------------------------------------------------------------------------
// Prep: fused transpose-to-bf16 (blocks < nconv) + gating (blocks >= nconv).
// ---------------------------------------------------------------------------
__global__ __launch_bounds__(256) void moe_prep(
    const float* __restrict__ W1, const float* __restrict__ W2,
    u16* __restrict__ w1t, u16* __restrict__ w2t, int nconv,
    const float* __restrict__ x, const float* __restrict__ Wg,
    const float* __restrict__ bg, float* __restrict__ gates,
    int2* __restrict__ recE, float2* __restrict__ recG,
    u16* __restrict__ xb, int write_xb, int* __restrict__ counts)
{
    __shared__ u16 th[64][65];
    const int idx = blockIdx.x;
    if (idx < nconv) {
        const int z  = idx >> 8;            // 0..15
        const int e  = z & 7;
        const bool isW2 = z >= 8;
        const float* in = isW2 ? W2 : W1;
        u16* ob         = isW2 ? w2t : w1t;
        const int R = isW2 ? H_DIM : D_IN;
        const int C = isW2 ? D_IN : H_DIM;
        const size_t base = (size_t)e * R * C;
        const int rem = idx & 255;
        const int bx = rem & 31, by = rem >> 5;
        const int c0 = (isW2 ? by : bx) * 64;
        const int r0 = (isW2 ? bx : by) * 64;
        const int c  = threadIdx.x & 63, rq = threadIdx.x >> 6;

#pragma unroll
        for (int i = 0; i < 16; ++i) {
            int r = rq * 16 + i;
            th[r][c] = bf16_rne(in[base + (size_t)(r0 + r) * C + c0 + c]);
        }
        __syncthreads();
#pragma unroll
        for (int i = 0; i < 16; ++i) {
            int rw = rq * 16 + i;
            ob[base + (size_t)(c0 + rw) * R + r0 + c] = th[c][rw];
        }
    } else {
        const int g = idx - nconv;
        if (g == 0 && threadIdx.x < N_EXP) counts[threadIdx.x] = 0;
        const int n = g * 4 + (threadIdx.x >> 6);
        const int l = threadIdx.x & 63;
        gate_one(n, l, x, Wg, bg, gates, recE, recG, xb, write_xb);
    }
}

// ---------------------------------------------------------------------------
// List build: 64 blocks (expert e = bid>>3, 512-token chunk).
// ---------------------------------------------------------------------------
__global__ __launch_bounds__(256) void build_lists(
    const int2* __restrict__ recE, const float2* __restrict__ recG,
    int* __restrict__ counts, int* __restrict__ lists, float* __restrict__ cwA,
    int* __restrict__ slotRec)
{
    __shared__ int cnt, base;
    __shared__ int   ltok[512];
    __shared__ float lcw[512];
    __shared__ int   lsrc[512];
    const int e  = blockIdx.x >> 3;
    const int c0 = (blockIdx.x & 7) * 512;
    const int tid = threadIdx.x;
    if (tid == 0) cnt = 0;
    __syncthreads();
#pragma unroll
    for (int it = 0; it < 2; ++it) {
        int t = c0 + it * 256 + tid;
        int2   ee = recE[t];
        float2 gg = recG[t];
        if (ee.x == e) {
            int p = atomicAdd(&cnt, 1);
            ltok[p] = t;  lcw[p] = gg.x;  lsrc[p] = 2 * t;
        }
        if (ee.y == e) {
            int p = atomicAdd(&cnt, 1);
            ltok[p] = t;  lcw[p] = gg.y;  lsrc[p] = 2 * t + 1;
        }
    }
    __syncthreads();
    if (tid == 0) base = atomicAdd(&counts[e], cnt);
    __syncthreads();
    const int c = cnt, b0 = base;
    for (int i = tid; i < c; i += 256) {
        int p = b0 + i;
        lists[e * N_TOK + p] = ltok[i];
        cwA[e * N_TOK + p]   = lcw[i];
        if (slotRec) slotRec[lsrc[i]] = p;
    }
}

#define BARX do { __builtin_amdgcn_s_barrier();                               \
                  __builtin_amdgcn_sched_barrier(0); } while (0)

// ---------------------------------------------------------------------------
// v11 expert kernel: TM=64, SPLIT=4 (2 si/block), double-buffered staging.
//   grid = 8 * 4 * MAXT64 = 640; e = b&7 (XCD affinity); hs = (b>>3)&3;
//   t = b>>5. Per si: G1 16 steps (stage 16KB W1 chunk + 4KB x chunk) ->
//   hT[64][256] -> G2 16 steps (stage 16KB W2 chunk). 16 MFMA/step/wave.
//   Step: {vmcnt(0); s_barrier; stage next chunk -> other buf; MFMA}.
//   accY[4][4][2] f32x4 = 128 VGPR persistent. y partials stored bf16.
// LDS: sB 32KB + sA 8KB + hT 33.8KB = ~73.5KB -> 2 blocks/CU.
// ---------------------------------------------------------------------------
#define S64G1(si_, ks_, buf_)                                                 \
    do {                                                                      \
        const u16* _s = w1E + (size_t)(si_) * (HS * D_IN) + (ks_) * 32;       \
        _Pragma("unroll")                                                     \
        for (int _i = 0; _i < 4; ++_i)                                        \
            async16(_s + bOffB[_i], &sB[buf_][dstB + _i * 512]);              \
        async16(xb + aOffW + (ks_) * 32, &sA[buf_][dstA]);                    \
    } while (0)

#define S64G2(si_, u2_, buf_)                                                 \
    do {                                                                      \
        const int _nc = (u2_) >> 2, _k2 = (u2_) & 3;                          \
        const u16* _s = w2E + (size_t)_nc * (128 * H_DIM) + (si_) * HS + _k2 * 64; \
        _Pragma("unroll")                                                     \
        for (int _i = 0; _i < 4; ++_i)                                        \
            async16(_s + bOff2[_i], &sB[buf_][dstB + _i * 512]);              \
    } while (0)

__global__ __launch_bounds__(256, 2) void moe_expert_64(
    const u16* __restrict__ xb,
    const u16* __restrict__ w1t, const u16* __restrict__ w2t,
    const float* __restrict__ b1, const float* __restrict__ b2,
    u16* __restrict__ y,
    const int* __restrict__ counts, const int* __restrict__ lists,
    const float* __restrict__ cwA)
{
    const int b  = blockIdx.x;
    const int e  = b & 7;            // expert -> XCD affinity
    const int q  = b >> 3;
    const int hs = q & 3;            // H quarter (2 si)
    const int t  = q >> 2;           // token tile 0..MAXT64-1
    int cnt = counts[e];
    if (cnt > YROWS) cnt = YROWS;
    if (t * 64 >= cnt) return;

    __shared__ __align__(16) u16 sB[2][8192];    // 32 KB: dbuf 16KB chunks
    __shared__ __align__(16) u16 sA[2][2048];    //  8 KB: dbuf 64x32 x chunks
    __shared__ __align__(16) u16 hT[64 * HROW];  // 33.8 KB
    __shared__ int   tokS[64];
    __shared__ float cwS[64];

    const int tid  = threadIdx.x;
    const int w    = tid >> 6;
    const int lane = tid & 63;
    const int quad = lane >> 4;
    const int l16  = lane & 15;

    if (tid < 64) {
        int gi = t * 64 + tid;
        bool v = gi < cnt;
        tokS[tid] = v ? lists[e * N_TOK + gi] : 0;
        cwS[tid]  = v ? cwA[e * N_TOK + gi] : 0.f;   // cw=0 kills pad rows
    }
    __syncthreads();

    // ---- staging geometry (lds dest = wave base + lane*16B) ----
    const int r4   = lane >> 2;                       // 16 rows/inst
    const int csw1 = (lane & 3) ^ ((lane >> 4) & 3);  // key=(row>>2)&3
    const int r8   = lane >> 3;                       // 8 rows/inst
    const int csw2 = (lane & 7) ^ r8;                 // key=row&7
    const int dstB = w * 2048 + lane * 8;             // u16 offset in sB buf
    const int dstA = w * 512 + lane * 8;              // u16 offset in sA buf

    // ---- fragment read offsets (u16 elements, within a buffer) ----
    int fB1[4], fA1[4];
#pragma unroll
    for (int nt = 0; nt < 4; ++nt) {
        int r = w * 64 + nt * 16 + l16;
        fB1[nt] = r * 32 + (quad ^ ((l16 >> 2) & 3)) * 8;
    }
#pragma unroll
    for (int m = 0; m < 4; ++m) {
        int r = m * 16 + l16;
        fA1[m] = r * 32 + (quad ^ ((l16 >> 2) & 3)) * 8;
    }
    int fB2[2][2], fA2[4];
#pragma unroll
    for (int nt = 0; nt < 2; ++nt)
#pragma unroll
        for (int kk = 0; kk < 2; ++kk) {
            int r = w * 32 + nt * 16 + l16;
            fB2[nt][kk] = r * 64 + (((kk * 4 + quad) ^ (l16 & 7)) * 8);
        }
#pragma unroll
    for (int m = 0; m < 4; ++m)
        fA2[m] = (m * 16 + l16) * HROW + quad * 8;

    // ---- global staging offsets ----
    const u16* w1E = w1t + (size_t)e * H_DIM * D_IN;
    const u16* w2E = w2t + (size_t)e * D_IN * H_DIM;
    int bOffB[4];
#pragma unroll
    for (int i = 0; i < 4; ++i)
        bOffB[i] = (w * 64 + i * 16 + r4) * D_IN + csw1 * 8;
    int bOff2[4];
#pragma unroll
    for (int i = 0; i < 4; ++i)
        bOff2[i] = (w * 32 + i * 8 + r8) * H_DIM + csw2 * 8;
    const int aOffW = tokS[w * 16 + r4] * D_IN + csw1 * 8;

    // ---- persistent output accumulator: y[64][512] over this H range ----
    f32x4 accY[4][4][2];
#pragma unroll
    for (int nc = 0; nc < 4; ++nc)
#pragma unroll
        for (int m = 0; m < 4; ++m)
#pragma unroll
            for (int nt = 0; nt < 2; ++nt)
                accY[nc][m][nt] = (f32x4){0.f, 0.f, 0.f, 0.f};

    // prologue: stage first G1 chunk of first si into buf 0
    S64G1(hs * 2, 0, 0);

    for (int sq = 0; sq < 2; ++sq) {
        const int si = hs * 2 + sq;
        float b1v[4];
#pragma unroll
        for (int nt = 0; nt < 4; ++nt)
            b1v[nt] = b1[e * H_DIM + si * HS + w * 64 + nt * 16 + l16];

        // -------- GEMM1: h[64][256] = xb-tile @ W1T-slice(si) --------
        f32x4 acc1[4][4];
#pragma unroll
        for (int m = 0; m < 4; ++m)
#pragma unroll
            for (int nt = 0; nt < 4; ++nt) acc1[m][nt] = (f32x4){0.f, 0.f, 0.f, 0.f};

#pragma unroll
        for (int u = 0; u < 16; ++u) {
            asm volatile("s_waitcnt vmcnt(0)" ::: "memory");
            BARX;
            if (u < 15) { S64G1(si, u + 1, (u + 1) & 1); }
            else        { S64G2(si, 0, 0); }            // u=15 computes buf1

            const u16* Bp = &sB[u & 1][0];
            const u16* Ap = &sA[u & 1][0];
            short8 bf[4], af[4];
#pragma unroll
            for (int nt = 0; nt < 4; ++nt) bf[nt] = *(const short8*)(Bp + fB1[nt]);
#pragma unroll
            for (int m = 0; m < 4; ++m)  af[m] = *(const short8*)(Ap + fA1[m]);
            __builtin_amdgcn_s_setprio(1);
#pragma unroll
            for (int nt = 0; nt < 4; ++nt)
#pragma unroll
                for (int m = 0; m < 4; ++m)
                    acc1[m][nt] = __builtin_amdgcn_mfma_f32_16x16x32_bf16(
                        af[m], bf[nt], acc1[m][nt], 0, 0, 0);
            __builtin_amdgcn_s_setprio(0);
        }

        // -------- epilogue 1: bias + relu -> hT (bf16) --------
#pragma unroll
        for (int nt = 0; nt < 4; ++nt) {
            const int c = w * 64 + nt * 16 + l16;
#pragma unroll
            for (int m = 0; m < 4; ++m)
#pragma unroll
                for (int r = 0; r < 4; ++r) {
                    int row = m * 16 + quad * 4 + r;
                    hT[row * HROW + c] = bf16_rne(fmaxf(acc1[m][nt][r] + b1v[nt], 0.f));
                }
        }
        asm volatile("s_waitcnt lgkmcnt(0)" ::: "memory");

        // -------- GEMM2: accY += hT @ W2T-slice(si) --------
#pragma unroll
        for (int u = 0; u < 16; ++u) {
            asm volatile("s_waitcnt vmcnt(0)" ::: "memory");
            BARX;                                   // also publishes hT at u=0
            if (u < 15)      { S64G2(si, u + 1, (u + 1) & 1); }
            else if (sq == 0){ S64G1(si + 1, 0, 0); }   // u=15 computes buf1

            const int nc = u >> 2, k2 = u & 3;
            const u16* Bp = &sB[u & 1][0];
#pragma unroll
            for (int kk = 0; kk < 2; ++kk) {
                short8 a0 = *(const short8*)(hT + fA2[0] + k2 * 64 + kk * 32);
                short8 a1 = *(const short8*)(hT + fA2[1] + k2 * 64 + kk * 32);
                short8 a2 = *(const short8*)(hT + fA2[2] + k2 * 64 + kk * 32);
                short8 a3 = *(const short8*)(hT + fA2[3] + k2 * 64 + kk * 32);
                short8 b0  = *(const short8*)(Bp + fB2[0][kk]);
                short8 b1f = *(const short8*)(Bp + fB2[1][kk]);
                __builtin_amdgcn_s_setprio(1);
                accY[nc][0][0] = __builtin_amdgcn_mfma_f32_16x16x32_bf16(a0, b0,  accY[nc][0][0], 0, 0, 0);
                accY[nc][1][0] = __builtin_amdgcn_mfma_f32_16x16x32_bf16(a1, b0,  accY[nc][1][0], 0, 0, 0);
                accY[nc][2][0] = __builtin_amdgcn_mfma_f32_16x16x32_bf16(a2, b0,  accY[nc][2][0], 0, 0, 0);
                accY[nc][3][0] = __builtin_amdgcn_mfma_f32_16x16x32_bf16(a3, b0,  accY[nc][3][0], 0, 0, 0);
                accY[nc][0][1] = __builtin_amdgcn_mfma_f32_16x16x32_bf16(a0, b1f, accY[nc][0][1], 0, 0, 0);
                accY[nc][1][1] = __builtin_amdgcn_mfma_f32_16x16x32_bf16(a1, b1f, accY[nc][1][1], 0, 0, 0);
                accY[nc][2][1] = __builtin_amdgcn_mfma_f32_16x16x32_bf16(a2, b1f, accY[nc][2][1], 0, 0, 0);
                accY[nc][3][1] = __builtin_amdgcn_mfma_f32_16x16x32_bf16(a3, b1f, accY[nc][3][1], 0, 0, 0);
                __builtin_amdgcn_s_setprio(0);
            }
        }
    }

    // ---- epilogue: bf16 y partial write: (acc [+b2 at hs0]) * cw ----
    u16* yT = y + (((size_t)e * 4 + hs) * YROWS + (size_t)t * 64) * D_IN;
#pragma unroll
    for (int nc = 0; nc < 4; ++nc)
#pragma unroll
        for (int nt = 0; nt < 2; ++nt) {
            const int dcol = nc * 128 + w * 32 + nt * 16 + l16;
            const float bias = (hs == 0) ? b2[e * D_IN + dcol] : 0.f;
#pragma unroll
            for (int m = 0; m < 4; ++m)
#pragma unroll
                for (int r = 0; r < 4; ++r) {
                    const int row = m * 16 + quad * 4 + r;
                    yT[(size_t)row * D_IN + dcol] =
                        bf16_rne((accY[nc][m][nt][r] + bias) * cwS[row]);
                }
        }
}

// ---------------------------------------------------------------------------
// Combine (mode3): out[t] = sum over k in {1,2}, hs in 0..3 of bf16 partials.
// ---------------------------------------------------------------------------
__global__ __launch_bounds__(256) void moe_combine_b4(
    const u16* __restrict__ y, const int* __restrict__ slotRec,
    const int2* __restrict__ recE, float* __restrict__ out)
{
    const int t  = blockIdx.x * 2 + (threadIdx.x >> 7);
    const int c4 = (threadIdx.x & 127) << 2;
    const int2 ee = recE[t];
    int s1 = slotRec[2 * t + 0];
    int s2 = slotRec[2 * t + 1];
    s1 = s1 < YROWS ? s1 : YROWS - 1;   // safety clamp
    s2 = s2 < YROWS ? s2 : YROWS - 1;
    float acc[4] = {0.f, 0.f, 0.f, 0.f};
#pragma unroll
    for (int h = 0; h < 4; ++h) {
        s16x4 a = *(const s16x4*)(
            y + (((size_t)ee.x * 4 + h) * YROWS + s1) * D_IN + c4);
        s16x4 bb = *(const s16x4*)(
            y + (((size_t)ee.y * 4 + h) * YROWS + s2) * D_IN + c4);
#pragma unroll
        for (int j = 0; j < 4; ++j)
            acc[j] += bf16_to_f32((u16)a[j]) + bf16_to_f32((u16)bb[j]);
    }
    *(float4*)(out + (size_t)t * D_IN + c4) =
        make_float4(acc[0], acc[1], acc[2], acc[3]);
}

// ---------------------------------------------------------------------------
// mode2 fallback: r8 SPLIT=1 TM=32 kernel (known-passing), f32 y.
// ---------------------------------------------------------------------------
#define STG1(si_, ks_, buf_)                                                  \
    do {                                                                      \
        const u16* _s = w1E + (size_t)(si_) * (HS * D_IN) + (ks_) * 32;       \
        _Pragma("unroll")                                                     \
        for (int _i = 0; _i < 4; ++_i)                                        \
            async16(_s + bOffB[_i], &sB[buf_][dstB + _i * 512]);              \
        if (w < 2)                                                            \
            async16(xb + aOffW + (ks_) * 32, &sA[buf_][w * 512 + lane * 8]);  \
    } while (0)

#define STG2(si_, u2_, buf_)                                                  \
    do {                                                                      \
        const int _nc = (u2_) >> 2, _k2 = (u2_) & 3;                          \
        const u16* _s = w2E + (size_t)_nc * (128 * H_DIM) + (si_) * HS + _k2 * 64; \
        _Pragma("unroll")                                                     \
        for (int _i = 0; _i < 4; ++_i)                                        \
            async16(_s + bOff2[_i], &sB[buf_][dstB + _i * 512]);              \
    } while (0)

__global__ __launch_bounds__(256, 2) void moe_expert_mfma2(
    const u16* __restrict__ xb,
    const u16* __restrict__ w1t, const u16* __restrict__ w2t,
    const float* __restrict__ b1, const float* __restrict__ b2,
    float* __restrict__ y,
    const int* __restrict__ counts, const int* __restrict__ lists,
    const float* __restrict__ cwA)
{
    const int b = blockIdx.x;
    const int e = b & 7;
    const int t = b >> 3;
    int cnt = counts[e];
    if (cnt > YROWS) cnt = YROWS;
    if (t * TM >= cnt) return;

    __shared__ __align__(16) u16 sB[3][8192];
    __shared__ __align__(16) u16 sA[3][1024];
    __shared__ __align__(16) u16 hT[TM * HROW];
    __shared__ int   tokS[TM];
    __shared__ float cwS[TM];

    const int tid  = threadIdx.x;
    const int w    = tid >> 6;
    const int lane = tid & 63;
    const int quad = lane >> 4;
    const int l16  = lane & 15;

    if (tid < TM) {
        int gi = t * TM + tid;
        bool v = gi < cnt;
        tokS[tid] = v ? lists[e * N_TOK + gi] : 0;
        cwS[tid]  = v ? cwA[e * N_TOK + gi] : 0.f;
    }
    __syncthreads();

    const int r4   = lane >> 2;
    const int csw1 = (lane & 3) ^ ((lane >> 4) & 3);
    const int r8   = lane >> 3;
    const int csw2 = (lane & 7) ^ r8;
    const int dstB = w * 2048 + lane * 8;

    int fB1[4], fA1[2];
#pragma unroll
    for (int nt = 0; nt < 4; ++nt) {
        int r = w * 64 + nt * 16 + l16;
        fB1[nt] = r * 32 + (quad ^ ((l16 >> 2) & 3)) * 8;
    }
#pragma unroll
    for (int m = 0; m < 2; ++m) {
        int r = m * 16 + l16;
        fA1[m] = r * 32 + (quad ^ ((l16 >> 2) & 3)) * 8;
    }
    int fB2[2][2], fA2[2];
#pragma unroll
    for (int nt = 0; nt < 2; ++nt)
#pragma unroll
        for (int kk = 0; kk < 2; ++kk) {
            int r = w * 32 + nt * 16 + l16;
            fB2[nt][kk] = r * 64 + (((kk * 4 + quad) ^ (l16 & 7)) * 8);
        }
#pragma unroll
    for (int m = 0; m < 2; ++m)
        fA2[m] = (m * 16 + l16) * HROW + quad * 8;

    const u16* w1E = w1t + (size_t)e * H_DIM * D_IN;
    const u16* w2E = w2t + (size_t)e * D_IN * H_DIM;
    int bOffB[4];
#pragma unroll
    for (int i = 0; i < 4; ++i)
        bOffB[i] = (w * 64 + i * 16 + r4) * D_IN + csw1 * 8;
    int bOff2[4];
#pragma unroll
    for (int i = 0; i < 4; ++i)
        bOff2[i] = (w * 32 + i * 8 + r8) * H_DIM + csw2 * 8;
    int aOffW = 0;
    if (w < 2) aOffW = tokS[w * 16 + r4] * D_IN + csw1 * 8;

    f32x4 accY[4][2][2];
#pragma unroll
    for (int nc = 0; nc < 4; ++nc)
#pragma unroll
        for (int m = 0; m < 2; ++m)
#pragma unroll
            for (int nt = 0; nt < 2; ++nt)
                accY[nc][m][nt] = (f32x4){0.f, 0.f, 0.f, 0.f};

    for (int si = 0; si < 8; ++si) {
        float b1v[4];
#pragma unroll
        for (int nt = 0; nt < 4; ++nt)
            b1v[nt] = b1[e * H_DIM + si * HS + w * 64 + nt * 16 + l16];

        STG1(si, 0, 0);

        f32x4 acc1[2][4];
#pragma unroll
        for (int m = 0; m < 2; ++m)
#pragma unroll
            for (int nt = 0; nt < 4; ++nt) acc1[m][nt] = (f32x4){0.f, 0.f, 0.f, 0.f};

#pragma unroll
        for (int u = 0; u < 16; ++u) {
            if (u == 0) {
                asm volatile("s_waitcnt vmcnt(0)" ::: "memory");
            } else if (u < 15) {
                if (w < 2) asm volatile("s_waitcnt vmcnt(5)" ::: "memory");
                else       asm volatile("s_waitcnt vmcnt(4)" ::: "memory");
            } else {
                asm volatile("s_waitcnt vmcnt(4)" ::: "memory");
            }
            BARX;
            if (u == 0)       { STG1(si, 1, 1); STG1(si, 2, 2); }
            else if (u < 14)  { STG1(si, u + 2, (u + 2) % 3); }
            else if (u == 14) { STG2(si, 0, 1); }
            else              { STG2(si, 1, 2); }

            const u16* Bp = &sB[u % 3][0];
            const u16* Ap = &sA[u % 3][0];
            short8 bf[4], af[2];
#pragma unroll
            for (int nt = 0; nt < 4; ++nt) bf[nt] = *(const short8*)(Bp + fB1[nt]);
#pragma unroll
            for (int m = 0; m < 2; ++m)  af[m] = *(const short8*)(Ap + fA1[m]);
            __builtin_amdgcn_s_setprio(1);
#pragma unroll
            for (int nt = 0; nt < 4; ++nt)
#pragma unroll
                for (int m = 0; m < 2; ++m)
                    acc1[m][nt] = __builtin_amdgcn_mfma_f32_16x16x32_bf16(
                        af[m], bf[nt], acc1[m][nt], 0, 0, 0);
            __builtin_amdgcn_s_setprio(0);
        }

#pragma unroll
        for (int nt = 0; nt < 4; ++nt) {
            const int c = w * 64 + nt * 16 + l16;
#pragma unroll
            for (int m = 0; m < 2; ++m)
#pragma unroll
                for (int r = 0; r < 4; ++r) {
                    int row = m * 16 + quad * 4 + r;
                    hT[row * HROW + c] = bf16_rne(fmaxf(acc1[m][nt][r] + b1v[nt], 0.f));
                }
        }

#pragma unroll
        for (int u = 0; u < 16; ++u) {
            if (u == 0)      asm volatile("s_waitcnt vmcnt(4) lgkmcnt(0)" ::: "memory");
            else if (u < 15) asm volatile("s_waitcnt vmcnt(4)" ::: "memory");
            else             asm volatile("s_waitcnt vmcnt(0)" ::: "memory");
            BARX;
            if (u < 14) STG2(si, u + 2, u % 3);

            const int nc = u >> 2, k2 = u & 3;
            const u16* Bp = &sB[(u + 1) % 3][0];
#pragma unroll
            for (int kk = 0; kk < 2; ++kk) {
                short8 a0  = *(const short8*)(hT + fA2[0] + k2 * 64 + kk * 32);
                short8 a1  = *(const short8*)(hT + fA2[1] + k2 * 64 + kk * 32);
                short8 b0  = *(const short8*)(Bp + fB2[0][kk]);
                short8 b1f = *(const short8*)(Bp + fB2[1][kk]);
                __builtin_amdgcn_s_setprio(1);
                accY[nc][0][0] = __builtin_amdgcn_mfma_f32_16x16x32_bf16(a0, b0,  accY[nc][0][0], 0, 0, 0);
                accY[nc][1][0] = __builtin_amdgcn_mfma_f32_16x16x32_bf16(a1, b0,  accY[nc][1][0], 0, 0, 0);
                accY[nc][0][1] = __builtin_amdgcn_mfma_f32_16x16x32_bf16(a0, b1f, accY[nc][0][1], 0, 0, 0);
                accY[nc][1][1] = __builtin_amdgcn_mfma_f32_16x16x32_bf16(a1, b1f, accY[nc][1][1], 0, 0, 0);
                __builtin_amdgcn_s_setprio(0);
            }
        }
    }

    float* yT = y + ((size_t)e * YROWS + (size_t)t * TM) * D_IN;
#pragma unroll
    for (int nc = 0; nc < 4; ++nc)
#pragma unroll
        for (int nt = 0; nt < 2; ++nt) {
            const int dcol = nc * 128 + w * 32 + nt * 16 + l16;
            const float bias = b2[e * D_IN + dcol];
#pragma unroll
            for (int m = 0; m < 2; ++m)
#pragma unroll
                for (int r = 0; r < 4; ++r) {
                    const int row = m * 16 + quad * 4 + r;
                    yT[(size_t)row * D_IN + dcol] =
                        (accY[nc][m][nt][r] + bias) * cwS[row];
                }
        }
}

// ---------------------------------------------------------------------------
// Combine (mode2): out[t] = y[e1][slot1] + y[e2][slot2]  (f32 y).
// ---------------------------------------------------------------------------
__global__ __launch_bounds__(256) void moe_combine_f1(
    const float* __restrict__ y, const int* __restrict__ slotRec,
    const int2* __restrict__ recE, float* __restrict__ out)
{
    const int t  = blockIdx.x * 2 + (threadIdx.x >> 7);
    const int c4 = (threadIdx.x & 127) << 2;
    const int2 ee = recE[t];
    int s1 = slotRec[2 * t + 0];
    int s2 = slotRec[2 * t + 1];
    s1 = s1 < YROWS ? s1 : YROWS - 1;
    s2 = s2 < YROWS ? s2 : YROWS - 1;
    const float4 a  = *(const float4*)(y + ((size_t)ee.x * YROWS + s1) * D_IN + c4);
    const float4 bb = *(const float4*)(y + ((size_t)ee.y * YROWS + s2) * D_IN + c4);
    *(float4*)(out + (size_t)t * D_IN + c4) =
        make_float4(a.x + bb.x, a.y + bb.y, a.z + bb.z, a.w + bb.w);
}

// ---------------------------------------------------------------------------
// r6 single-pass bf16 expert kernel (known-passing) — mode1 fallback.
// ---------------------------------------------------------------------------
__global__ __launch_bounds__(256, 4) void moe_expert_mfma(
    const u16* __restrict__ xb,
    const u16* __restrict__ w1t, const u16* __restrict__ w2t,
    const float* __restrict__ b1, const float* __restrict__ b2,
    float* __restrict__ out,
    const int* __restrict__ counts, const int* __restrict__ lists,
    const float* __restrict__ cwA)
{
    const int b = blockIdx.x;
    const int s = b & 7;
    const int q = b >> 3;
    const int t = q % MAXT;
    const int e = q / MAXT;
    const int cnt = counts[e];
    if (t * TM >= cnt) return;

    __shared__ __align__(16) u16 sB[8192];
    __shared__ __align__(16) u16 sA[1024];
    __shared__ __align__(16) u16 hT[TM * HROW];
    __shared__ int   tokS[TM];
    __shared__ float cwS[TM];

    const int tid  = threadIdx.x;
    const int w    = tid >> 6;
    const int lane = tid & 63;
    const int quad = lane >> 4;
    const int l16  = lane & 15;

    if (tid < TM) {
        int gi = t * TM + tid;
        bool v = gi < cnt;
        tokS[tid] = v ? lists[e * N_TOK + gi] : 0;
        cwS[tid]  = v ? cwA[e * N_TOK + gi] : 0.f;
    }
    __syncthreads();

    const int r4   = lane >> 2;
    const int csw1 = (lane & 3) ^ ((lane >> 4) & 3);
    const int r8   = lane >> 3;
    const int csw2 = (lane & 7) ^ r8;
    u16* ldsB0 = sB + w * 2048 + lane * 8;
    u16* ldsA0 = sA + lane * 8;

    int fB1[4], fA1[2];
#pragma unroll
    for (int nt = 0; nt < 4; ++nt) {
        int r = w * 64 + nt * 16 + l16;
        fB1[nt] = r * 32 + (quad ^ ((l16 >> 2) & 3)) * 8;
    }
#pragma unroll
    for (int m = 0; m < 2; ++m) {
        int r = m * 16 + l16;
        fA1[m] = r * 32 + (quad ^ ((l16 >> 2) & 3)) * 8;
    }
    int fB2[2][2], fA2[2];
#pragma unroll
    for (int nt = 0; nt < 2; ++nt)
#pragma unroll
        for (int kk = 0; kk < 2; ++kk) {
            int r = w * 32 + nt * 16 + l16;
            fB2[nt][kk] = r * 64 + (((kk * 4 + quad) ^ (l16 & 7)) * 8);
        }
#pragma unroll
    for (int m = 0; m < 2; ++m)
        fA2[m] = (m * 16 + l16) * HROW + quad * 8;

    int bOffB[4];
#pragma unroll
    for (int i = 0; i < 4; ++i)
        bOffB[i] = (s * HS + w * 64 + i * 16 + r4) * D_IN + csw1 * 8;
    int aOff0 = tokS[r4]      * D_IN + csw1 * 8;
    int aOff1 = tokS[16 + r4] * D_IN + csw1 * 8;
    const u16* w1E = w1t + (size_t)e * H_DIM * D_IN;

    f32x4 acc1[2][4];
#pragma unroll
    for (int m = 0; m < 2; ++m)
#pragma unroll
        for (int nt = 0; nt < 4; ++nt) acc1[m][nt] = (f32x4){0.f, 0.f, 0.f, 0.f};

    for (int ks = 0; ks < 16; ++ks) {
        const int kb = ks * 32;
        __syncthreads();
#pragma unroll
        for (int i = 0; i < 4; ++i)
            async16(w1E + bOffB[i] + kb, ldsB0 + i * 512);
        if (w == 0) {
            async16(xb + aOff0 + kb, ldsA0);
            async16(xb + aOff1 + kb, ldsA0 + 512);
        }
        __syncthreads();
        short8 bf[4], af[2];
#pragma unroll
        for (int nt = 0; nt < 4; ++nt) bf[nt] = *(const short8*)(sB + fB1[nt]);
#pragma unroll
        for (int m = 0; m < 2; ++m)  af[m] = *(const short8*)(sA + fA1[m]);
#pragma unroll
        for (int nt = 0; nt < 4; ++nt)
#pragma unroll
            for (int m = 0; m < 2; ++m)
                acc1[m][nt] = __builtin_amdgcn_mfma_f32_16x16x32_bf16(af[m], bf[nt], acc1[m][nt], 0, 0, 0);
    }

#pragma unroll
    for (int nt = 0; nt < 4; ++nt) {
        const int c = w * 64 + nt * 16 + l16;
        const float bias = b1[e * H_DIM + s * HS + c];
#pragma unroll
        for (int m = 0; m < 2; ++m)
#pragma unroll
            for (int r = 0; r < 4; ++r) {
                int row = m * 16 + quad * 4 + r;
                hT[row * HROW + c] = bf16_rne(fmaxf(acc1[m][nt][r] + bias, 0.f));
            }
    }

    const u16* w2E = w2t + (size_t)e * D_IN * H_DIM;
    int bOff2[4];
#pragma unroll
    for (int i = 0; i < 4; ++i)
        bOff2[i] = (w * 32 + i * 8 + r8) * H_DIM + s * HS + csw2 * 8;

    for (int nc = 0; nc < 4; ++nc) {
        f32x4 acc2[2][2];
#pragma unroll
        for (int m = 0; m < 2; ++m)
#pragma unroll
            for (int nt = 0; nt < 2; ++nt) acc2[m][nt] = (f32x4){0.f, 0.f, 0.f, 0.f};

        for (int ks = 0; ks < 4; ++ks) {
            __syncthreads();
#pragma unroll
            for (int i = 0; i < 4; ++i)
                async16(w2E + bOff2[i] + nc * (128 * H_DIM) + ks * 64,
                        ldsB0 + i * 512);
            __syncthreads();
#pragma unroll
            for (int kk = 0; kk < 2; ++kk) {
                short8 a0  = *(const short8*)(hT + fA2[0] + ks * 64 + kk * 32);
                short8 a1  = *(const short8*)(hT + fA2[1] + ks * 64 + kk * 32);
                short8 b0  = *(const short8*)(sB + fB2[0][kk]);
                short8 b1f = *(const short8*)(sB + fB2[1][kk]);
                acc2[0][0] = __builtin_amdgcn_mfma_f32_16x16x32_bf16(a0, b0,  acc2[0][0], 0, 0, 0);
                acc2[1][0] = __builtin_amdgcn_mfma_f32_16x16x32_bf16(a1, b0,  acc2[1][0], 0, 0, 0);
                acc2[0][1] = __builtin_amdgcn_mfma_f32_16x16x32_bf16(a0, b1f, acc2[0][1], 0, 0, 0);
                acc2[1][1] = __builtin_amdgcn_mfma_f32_16x16x32_bf16(a1, b1f, acc2[1][1], 0, 0, 0);
            }
        }

#pragma unroll
        for (int nt = 0; nt < 2; ++nt) {
            const int dcol = nc * 128 + w * 32 + nt * 16 + l16;
            const float bias = (s == 0) ? b2[e * D_IN + dcol] : 0.f;
#pragma unroll
            for (int m = 0; m < 2; ++m)
#pragma unroll
                for (int r = 0; r < 4; ++r) {
                    int row = m * 16 + quad * 4 + r;
                    float v = (acc2[m][nt][r] + bias) * cwS[row];
                    atomicAdd(out + (size_t)tokS[row] * D_IN + dcol, v);
                }
        }
    }
}

// ---------------------------------------------------------------------------
// Fallback fp32 expert kernel (round 1, known-passing) — mode0.
// ---------------------------------------------------------------------------
__global__ __launch_bounds__(256, 4) void moe_expert_fp32(
    const float* __restrict__ x,  const float* __restrict__ W1,
    const float* __restrict__ b1, const float* __restrict__ W2,
    const float* __restrict__ b2, float* __restrict__ out,
    const int* __restrict__ counts, const int* __restrict__ lists,
    const float* __restrict__ cwA)
{
    const int e    = blockIdx.x & 7;
    const int tile = blockIdx.x >> 3;
    const int cnt  = counts[e];
    if (tile * 16 >= cnt) return;

    __shared__ float xs[16 * 520];
    __shared__ float hs[16 * 68];
    __shared__ int   tokS[16];
    __shared__ float cwS[16];

    const int tid = threadIdx.x;
    if (tid < 16) {
        int gi = tile * 16 + tid;
        bool v = gi < cnt;
        tokS[tid] = v ? lists[e * N_TOK + gi] : 0;
        cwS[tid]  = v ? cwA[e * N_TOK + gi]  : 0.f;
    }
    __syncthreads();
    {
        const int i = tid >> 4, p = tid & 15;
        const float* xr = x + (size_t)tokS[i] * D_IN + p * 32;
        float* xd = xs + i * 520 + p * 32;
#pragma unroll
        for (int qq = 0; qq < 8; ++qq)
            *(float4*)(xd + qq * 4) = *(const float4*)(xr + qq * 4);
    }
    __syncthreads();

    const float* W1e = W1 + (size_t)e * D_IN * H_DIM;
    const float* W2e = W2 + (size_t)e * H_DIM * D_IN;
    const int j = tid & 31, rg1 = tid >> 5, cg = tid & 63, rg2 = tid >> 6;

    float acc[4][8];
#pragma unroll
    for (int i = 0; i < 4; ++i)
#pragma unroll
        for (int m = 0; m < 8; ++m) acc[i][m] = 0.f;

    for (int hc = 0; hc < H_DIM / 64; ++hc) {
        float a1[2][2] = {{0.f, 0.f}, {0.f, 0.f}};
        const float* w1p = W1e + hc * 64 + j;
        for (int d = 0; d < D_IN; d += 4) {
            float xv[2][4];
            *(float4*)xv[0] = *(const float4*)(xs + (rg1 * 2 + 0) * 520 + d);
            *(float4*)xv[1] = *(const float4*)(xs + (rg1 * 2 + 1) * 520 + d);
#pragma unroll
            for (int dd = 0; dd < 4; ++dd) {
                float wa = w1p[(size_t)(d + dd) * H_DIM];
                float wb = w1p[(size_t)(d + dd) * H_DIM + 32];
                a1[0][0] = fmaf(xv[0][dd], wa, a1[0][0]);
                a1[0][1] = fmaf(xv[0][dd], wb, a1[0][1]);
                a1[1][0] = fmaf(xv[1][dd], wa, a1[1][0]);
                a1[1][1] = fmaf(xv[1][dd], wb, a1[1][1]);
            }
        }
        float b1a = b1[e * H_DIM + hc * 64 + j];
        float b1b = b1[e * H_DIM + hc * 64 + j + 32];
        __syncthreads();
        hs[(rg1 * 2 + 0) * 68 + j]      = fmaxf(a1[0][0] + b1a, 0.f);
        hs[(rg1 * 2 + 0) * 68 + j + 32] = fmaxf(a1[0][1] + b1b, 0.f);
        hs[(rg1 * 2 + 1) * 68 + j]      = fmaxf(a1[1][0] + b1a, 0.f);
        hs[(rg1 * 2 + 1) * 68 + j + 32] = fmaxf(a1[1][1] + b1b, 0.f);
        __syncthreads();
        const float* w2p = W2e + (size_t)(hc * 64) * D_IN + cg;
        for (int k = 0; k < 64; k += 4) {
            float hv[4][4];
#pragma unroll
            for (int i = 0; i < 4; ++i)
                *(float4*)hv[i] = *(const float4*)(hs + (rg2 * 4 + i) * 68 + k);
#pragma unroll
            for (int kk = 0; kk < 4; ++kk) {
                float w2r[8];
#pragma unroll
                for (int m = 0; m < 8; ++m)
                    w2r[m] = w2p[(size_t)(k + kk) * D_IN + 64 * m];
#pragma unroll
                for (int i = 0; i < 4; ++i)
#pragma unroll
                    for (int m = 0; m < 8; ++m)
                        acc[i][m] = fmaf(hv[i][kk], w2r[m], acc[i][m]);
            }
        }
        __syncthreads();
    }
    float b2v[8];
#pragma unroll
    for (int m = 0; m < 8; ++m) b2v[m] = b2[e * D_IN + cg + 64 * m];
#pragma unroll
    for (int i = 0; i < 4; ++i) {
        const int r = rg2 * 4 + i;
        const float cw = cwS[r];
        float* op = out + (size_t)tokS[r] * D_IN + cg;
#pragma unroll
        for (int m = 0; m < 8; ++m)
            atomicAdd(op + 64 * m, (acc[i][m] + b2v[m]) * cw);
    }
}

// ---------------------------------------------------------------------------
extern "C" void kernel_launch(void* const* d_in, const int* in_sizes, int n_in,
                              void* d_out, int out_size, void* d_ws, size_t ws_size,
                              hipStream_t stream) {
    const float* x  = (const float*)d_in[0];
    const float* Wg = (const float*)d_in[1];
    const float* bg = (const float*)d_in[2];
    const float* W1 = (const float*)d_in[3];
    const float* b1 = (const float*)d_in[4];
    const float* W2 = (const float*)d_in[5];
    const float* b2 = (const float*)d_in[6];

    float* out   = (float*)d_out;
    float* gates = out + (size_t)N_TOK * D_IN;

    // ws layout: counts | recE | recG | lists | cw | xb | w1t | w2t | slot | y
    const size_t o_recE  = 1024;
    const size_t o_recG  = o_recE + (size_t)N_TOK * 8;
    const size_t o_lists = o_recG + (size_t)N_TOK * 8;
    const size_t o_cw    = o_lists + (size_t)N_EXP * N_TOK * 4;
    const size_t o_xb    = o_cw + (size_t)N_EXP * N_TOK * 4;
    const size_t o_w1t   = o_xb + (size_t)N_TOK * D_IN * 2;
    const size_t o_w2t   = o_w1t + (size_t)N_EXP * D_IN * H_DIM * 2;
    const size_t o_slot  = o_w2t + (size_t)N_EXP * D_IN * H_DIM * 2;
    const size_t o_y     = o_slot + (size_t)N_TOK * 2 * 4;
    const size_t ybytes1 = (size_t)N_EXP * YROWS * D_IN * 4;         // f32 SPLIT1
    const size_t ybytesb = (size_t)N_EXP * 4 * YROWS * D_IN * 2;     // bf16 SPLIT4
    const size_t NEED1   = o_slot;                                   // ~38.1 MB
    const size_t NEED2   = o_y + ybytes1;                            // ~59.1 MB
    const size_t NEED3   = o_y + ybytesb;                            // ~80.1 MB

    int*    counts  = (int*)d_ws;
    int2*   recE    = (int2*)((char*)d_ws + o_recE);
    float2* recG    = (float2*)((char*)d_ws + o_recG);
    int*    lists   = (int*)((char*)d_ws + o_lists);
    float*  cwA     = (float*)((char*)d_ws + o_cw);
    u16*    xb      = (u16*)((char*)d_ws + o_xb);
    u16*    w1t     = (u16*)((char*)d_ws + o_w1t);
    u16*    w2t     = (u16*)((char*)d_ws + o_w2t);
    int*    slotRec = (int*)((char*)d_ws + o_slot);
    float*  ywsF    = (float*)((char*)d_ws + o_y);
    u16*    ywsB    = (u16*)((char*)d_ws + o_y);

    const int mode = (ws_size >= NEED3) ? 3 :
                     (ws_size >= NEED2) ? 2 :
                     (ws_size >= NEED1) ? 1 : 0;
    const int nconv = (mode >= 1) ? 4096 : 0;
    const int nprep = nconv + N_TOK / 4;      // gate: 4 tokens/block, 4 waves

    moe_prep<<<nprep, 256, 0, stream>>>(
        W1, W2, w1t, w2t, nconv,
        x, Wg, bg, gates, recE, recG, xb, mode >= 1 ? 1 : 0, counts);
    build_lists<<<64, 256, 0, stream>>>(recE, recG, counts, lists, cwA,
                                        mode >= 2 ? slotRec : (int*)nullptr);

    if (mode == 3) {
        moe_expert_64<<<N_EXP * 4 * MAXT64, 256, 0, stream>>>(
            xb, w1t, w2t, b1, b2, ywsB, counts, lists, cwA);
        moe_combine_b4<<<N_TOK / 2, 256, 0, stream>>>(ywsB, slotRec, recE, out);
    } else if (mode == 2) {
        moe_expert_mfma2<<<N_EXP * MAXT, 256, 0, stream>>>(
            xb, w1t, w2t, b1, b2, ywsF, counts, lists, cwA);
        moe_combine_f1<<<N_TOK / 2, 256, 0, stream>>>(ywsF, slotRec, recE, out);
    } else if (mode == 1) {
        hipMemsetAsync(d_out, 0, (size_t)N_TOK * D_IN * sizeof(float), stream);
        moe_expert_mfma<<<N_EXP * MAXT * 8, 256, 0, stream>>>(
            xb, w1t, w2t, b1, b2, out, counts, lists, cwA);
    } else {
        hipMemsetAsync(d_out, 0, (size_t)N_TOK * D_IN * sizeof(float), stream);
        moe_expert_fp32<<<N_EXP * 256, 256, 0, stream>>>(
            x, W1, b1, W2, b2, out, counts, lists, cwA);
    }
}

// Round 7
// 246.893 us; speedup vs baseline: 1.4447x; 1.0484x over previous
//
#include <hip/hip_runtime.h>
#include <math.h>
#include <stdint.h>

// MoE: E=8, top-2, D=512, H=2048, N=4096, fp32 in/out.
// Round 12: depth-2 counted-vmcnt pipeline at exactly-80KB LDS (2 blocks/CU).
//   r11 post-mortem: 135us, pace ~2000cy/step; FETCH 57.6MB vs 33.6 ideal ->
//   L2 thrash (4.2MB expert set > 4MB L2) -> drains eat HBM latency with only
//   a 1-step window. r12: W chunks staged 2 steps ahead (3x16KB rotation,
//   wait vmcnt(4) leaves next chunk in flight across 2 barriers). LDS diet:
//   hT linear 64x256 + XOR swizzle (32KB, kills the 4.3M bank conflicts);
//   x dbuf (2x4KB) OVERLAYS hT's first 8KB (temporally disjoint); tokS/cwS
//   to regs/global. sB 48 + hT&sA 32 = 80KB exact -> 2 blocks/CU.
//   Rotation mod 3 hand-audited across G1->G2->next-si (one vmcnt(0) bubble
//   per si-pair). b1 loads hoisted + sched_barrier-pinned to keep counts.
//   Fallbacks unchanged: mode2 = r8 SPLIT1 f32-y; mode1 = r6; mode0 = fp32.

#define N_TOK 4096
#define D_IN  512
#define H_DIM 2048
#define N_EXP 8
#define TM    32
#define HS    256
#define MAXT  40                // TM=32 tiling (fallback kernels)
#define MAXT64 20               // TM=64 tiling: 20*64 = 1280 slots
#define YROWS (MAXT * TM)       // 1280 y slots per expert
#define HROW  264               // u16 stride (fallback kernels only)

typedef float  f32x4  __attribute__((ext_vector_type(4)));
typedef short  short8 __attribute__((ext_vector_type(8)));
typedef short  s16x4  __attribute__((ext_vector_type(4)));
typedef unsigned short u16;

__device__ __forceinline__ u16 bf16_rne(float f) {
    uint32_t u = __float_as_uint(f);
    return (u16)((u + 0x7fffu + ((u >> 16) & 1u)) >> 16);
}
__device__ __forceinline__ float bf16_to_f32(u16 v) {
    return __uint_as_float(((uint32_t)v) << 16);
}
__device__ __forceinline__ void async16(const u16* g, u16* l) {
    __builtin_amdgcn_global_load_lds(
        (const __attribute__((address_space(1))) void*)g,
        (__attribute__((address_space(3))) void*)l, 16, 0, 0);
}

// ---------------------------------------------------------------------------
// Gate body: one wave per token.
// ---------------------------------------------------------------------------
__device__ __forceinline__ void gate_one(
    int n, int l,
    const float* __restrict__ x, const float* __restrict__ Wg,
    const float* __restrict__ bg, float* __restrict__ gates,
    int2* __restrict__ recE, float2* __restrict__ recG,
    u16* __restrict__ xb, int write_xb)
{
    const float* xr  = x + (size_t)n * D_IN + l * 8;
    const float* wgr = Wg + (size_t)l * 8 * N_EXP;

    float xv[8];
    *(float4*)&xv[0] = *(const float4*)xr;
    *(float4*)&xv[4] = *(const float4*)(xr + 4);

    if (write_xb) {
        short8 pk;
#pragma unroll
        for (int i = 0; i < 8; ++i) pk[i] = (short)bf16_rne(xv[i]);
        *(short8*)(xb + (size_t)n * D_IN + l * 8) = pk;
    }

    float acc[8] = {0.f, 0.f, 0.f, 0.f, 0.f, 0.f, 0.f, 0.f};
#pragma unroll
    for (int dd = 0; dd < 8; ++dd) {
        float4 wa = *(const float4*)(wgr + dd * N_EXP);
        float4 wb = *(const float4*)(wgr + dd * N_EXP + 4);
        acc[0] = fmaf(xv[dd], wa.x, acc[0]);
        acc[1] = fmaf(xv[dd], wa.y, acc[1]);
        acc[2] = fmaf(xv[dd], wa.z, acc[2]);
        acc[3] = fmaf(xv[dd], wa.w, acc[3]);
        acc[4] = fmaf(xv[dd], wb.x, acc[4]);
        acc[5] = fmaf(xv[dd], wb.y, acc[5]);
        acc[6] = fmaf(xv[dd], wb.z, acc[6]);
        acc[7] = fmaf(xv[dd], wb.w, acc[7]);
    }
#pragma unroll
    for (int off = 32; off >= 1; off >>= 1) {
#pragma unroll
        for (int e = 0; e < N_EXP; ++e)
            acc[e] += __shfl_xor(acc[e], off);
    }

    float g[8];
    float mx = -3.4e38f;
#pragma unroll
    for (int e = 0; e < N_EXP; ++e) { g[e] = acc[e] + bg[e]; mx = fmaxf(mx, g[e]); }
    float s = 0.f;
#pragma unroll
    for (int e = 0; e < N_EXP; ++e) { g[e] = expf(g[e] - mx); s += g[e]; }
    const float inv = 1.0f / s;
#pragma unroll
    for (int e = 0; e < N_EXP; ++e) g[e] *= inv;

    if (l == 0) {
        float* go = gates + (size_t)n * N_EXP;
        *(float4*)go       = make_float4(g[0], g[1], g[2], g[3]);
        *(float4*)(go + 4) = make_float4(g[4], g[5], g[6], g[7]);

        int e1 = 0; float g1 = g[0];
#pragma unroll
        for (int e = 1; e < N_EXP; ++e) if (g[e] > g1) { g1 = g[e]; e1 = e; }
        int e2 = -1; float g2 = -1.f;
#pragma unroll
        for (int e = 0; e < N_EXP; ++e) if (e != e1 && g[e] > g2) { g2 = g[e]; e2 = e; }

        recE[n] = make_int2(e1, e2);
        recG[n] = make_float2(g1, g2);
    }
}

// ---------------------------------------------------------------------------
// Prep: fused transpose-to-bf16 (blocks < nconv) + gating (blocks >= nconv).
// ---------------------------------------------------------------------------
__global__ __launch_bounds__(256) void moe_prep(
    const float* __restrict__ W1, const float* __restrict__ W2,
    u16* __restrict__ w1t, u16* __restrict__ w2t, int nconv,
    const float* __restrict__ x, const float* __restrict__ Wg,
    const float* __restrict__ bg, float* __restrict__ gates,
    int2* __restrict__ recE, float2* __restrict__ recG,
    u16* __restrict__ xb, int write_xb, int* __restrict__ counts)
{
    __shared__ u16 th[64][65];
    const int idx = blockIdx.x;
    if (idx < nconv) {
        const int z  = idx >> 8;            // 0..15
        const int e  = z & 7;
        const bool isW2 = z >= 8;
        const float* in = isW2 ? W2 : W1;
        u16* ob         = isW2 ? w2t : w1t;
        const int R = isW2 ? H_DIM : D_IN;
        const int C = isW2 ? D_IN : H_DIM;
        const size_t base = (size_t)e * R * C;
        const int rem = idx & 255;
        const int bx = rem & 31, by = rem >> 5;
        const int c0 = (isW2 ? by : bx) * 64;
        const int r0 = (isW2 ? bx : by) * 64;
        const int c  = threadIdx.x & 63, rq = threadIdx.x >> 6;

#pragma unroll
        for (int i = 0; i < 16; ++i) {
            int r = rq * 16 + i;
            th[r][c] = bf16_rne(in[base + (size_t)(r0 + r) * C + c0 + c]);
        }
        __syncthreads();
#pragma unroll
        for (int i = 0; i < 16; ++i) {
            int rw = rq * 16 + i;
            ob[base + (size_t)(c0 + rw) * R + r0 + c] = th[c][rw];
        }
    } else {
        const int g = idx - nconv;
        if (g == 0 && threadIdx.x < N_EXP) counts[threadIdx.x] = 0;
        const int n = g * 4 + (threadIdx.x >> 6);
        const int l = threadIdx.x & 63;
        gate_one(n, l, x, Wg, bg, gates, recE, recG, xb, write_xb);
    }
}

// ---------------------------------------------------------------------------
// List build: 64 blocks (expert e = bid>>3, 512-token chunk).
// ---------------------------------------------------------------------------
__global__ __launch_bounds__(256) void build_lists(
    const int2* __restrict__ recE, const float2* __restrict__ recG,
    int* __restrict__ counts, int* __restrict__ lists, float* __restrict__ cwA,
    int* __restrict__ slotRec)
{
    __shared__ int cnt, base;
    __shared__ int   ltok[512];
    __shared__ float lcw[512];
    __shared__ int   lsrc[512];
    const int e  = blockIdx.x >> 3;
    const int c0 = (blockIdx.x & 7) * 512;
    const int tid = threadIdx.x;
    if (tid == 0) cnt = 0;
    __syncthreads();
#pragma unroll
    for (int it = 0; it < 2; ++it) {
        int t = c0 + it * 256 + tid;
        int2   ee = recE[t];
        float2 gg = recG[t];
        if (ee.x == e) {
            int p = atomicAdd(&cnt, 1);
            ltok[p] = t;  lcw[p] = gg.x;  lsrc[p] = 2 * t;
        }
        if (ee.y == e) {
            int p = atomicAdd(&cnt, 1);
            ltok[p] = t;  lcw[p] = gg.y;  lsrc[p] = 2 * t + 1;
        }
    }
    __syncthreads();
    if (tid == 0) base = atomicAdd(&counts[e], cnt);
    __syncthreads();
    const int c = cnt, b0 = base;
    for (int i = tid; i < c; i += 256) {
        int p = b0 + i;
        lists[e * N_TOK + p] = ltok[i];
        cwA[e * N_TOK + p]   = lcw[i];
        if (slotRec) slotRec[lsrc[i]] = p;
    }
}

#define BARX do { __builtin_amdgcn_s_barrier();                               \
                  __builtin_amdgcn_sched_barrier(0); } while (0)

// ---------------------------------------------------------------------------
// v12 expert kernel: TM=64, SPLIT=4, depth-2 counted-vmcnt, 80KB LDS exact.
//   grid = 8 * 4 * MAXT64 = 640; e = b&7; hs = (b>>3)&3; t = b>>5.
//   sB: 3 x 16KB W-chunk rotation (buf = (chunkIdx + 32*sq) % 3).
//   hTsA[32KB]: hT linear [64][256] XOR-swizzled; first 8KB doubles as the
//   x-chunk dbuf during G1 (temporally disjoint from hT).
//   Step: wait vmcnt(4) (leaves next W chunk in flight -> 2-step window);
//   s_barrier; issue x(u+1)+W(u+2); 16 MFMA. vmcnt(0) only at si-pair entry.
// ---------------------------------------------------------------------------
#define W1CH(si_, k_, buf_)                                                   \
    do {                                                                      \
        const u16* _s = w1E + (size_t)(si_) * (HS * D_IN) + (k_) * 32;        \
        _Pragma("unroll")                                                     \
        for (int _i = 0; _i < 4; ++_i)                                        \
            async16(_s + bOffB[_i], &sB[buf_][dstB + _i * 512]);              \
    } while (0)

#define W2CH(si_, v_, buf_)                                                   \
    do {                                                                      \
        const int _nc = (v_) >> 2, _k2 = (v_) & 3;                            \
        const u16* _s = w2E + (size_t)_nc * (128 * H_DIM) + (si_) * HS + _k2 * 64; \
        _Pragma("unroll")                                                     \
        for (int _i = 0; _i < 4; ++_i)                                        \
            async16(_s + bOff2[_i], &sB[buf_][dstB + _i * 512]);              \
    } while (0)

#define XCH(k_, ab_)                                                          \
    async16(xb + aOffW + (k_) * 32, hTsA + (ab_) * 2048 + dstA)

__global__ __launch_bounds__(256, 2) void moe_expert_64b(
    const u16* __restrict__ xb,
    const u16* __restrict__ w1t, const u16* __restrict__ w2t,
    const float* __restrict__ b1, const float* __restrict__ b2,
    u16* __restrict__ y,
    const int* __restrict__ counts, const int* __restrict__ lists,
    const float* __restrict__ cwA)
{
    const int b  = blockIdx.x;
    const int e  = b & 7;            // expert -> XCD affinity
    const int q  = b >> 3;
    const int hs = q & 3;            // H quarter (2 si)
    const int t  = q >> 2;           // token tile 0..MAXT64-1
    int cnt = counts[e];
    if (cnt > YROWS) cnt = YROWS;
    if (t * 64 >= cnt) return;

    __shared__ __align__(16) u16 sB[3][8192];    // 48 KB: 3x16KB W chunks
    __shared__ __align__(16) u16 hTsA[16384];    // 32 KB: hT; [0:8KB) = x dbuf

    const int tid  = threadIdx.x;
    const int w    = tid >> 6;
    const int lane = tid & 63;
    const int quad = lane >> 4;
    const int l16  = lane & 15;

    // ---- staging geometry ----
    const int r4   = lane >> 2;
    const int csw1 = (lane & 3) ^ ((lane >> 4) & 3);
    const int r8   = lane >> 3;
    const int csw2 = (lane & 7) ^ r8;
    const int dstB = w * 2048 + lane * 8;
    const int dstA = w * 512 + lane * 8;

    // per-lane token id for x staging (replaces tokS LDS)
    const int gidx = t * 64 + w * 16 + r4;
    const int tokid = (gidx < cnt) ? lists[e * N_TOK + gidx] : 0;
    const int aOffW = tokid * D_IN + csw1 * 8;

    // ---- fragment read offsets ----
    int fB1[4], fA1[4];
#pragma unroll
    for (int nt = 0; nt < 4; ++nt) {
        int r = w * 64 + nt * 16 + l16;
        fB1[nt] = r * 32 + (quad ^ ((l16 >> 2) & 3)) * 8;
    }
#pragma unroll
    for (int m = 0; m < 4; ++m) {
        int r = m * 16 + l16;
        fA1[m] = r * 32 + (quad ^ ((l16 >> 2) & 3)) * 8;
    }
    int fB2[2][2];
#pragma unroll
    for (int nt = 0; nt < 2; ++nt)
#pragma unroll
        for (int kk = 0; kk < 2; ++kk) {
            int r = w * 32 + nt * 16 + l16;
            fB2[nt][kk] = r * 64 + (((kk * 4 + quad) ^ (l16 & 7)) * 8);
        }
    int rowb[4];
#pragma unroll
    for (int m = 0; m < 4; ++m) rowb[m] = (m * 16 + l16) * 256;
    const int hswz = (l16 & 7) << 3;    // hT read swizzle (row&7 == l16&7)
    const int qoff = quad * 8;

    // ---- global staging offsets ----
    const u16* w1E = w1t + (size_t)e * H_DIM * D_IN;
    const u16* w2E = w2t + (size_t)e * D_IN * H_DIM;
    int bOffB[4];
#pragma unroll
    for (int i = 0; i < 4; ++i)
        bOffB[i] = (w * 64 + i * 16 + r4) * D_IN + csw1 * 8;
    int bOff2[4];
#pragma unroll
    for (int i = 0; i < 4; ++i)
        bOff2[i] = (w * 32 + i * 8 + r8) * H_DIM + csw2 * 8;

    // b1 bias for both si, loaded up-front and pinned (oldest vmem; drained
    // by the first counted wait without disturbing the counts).
    float b1v[2][4];
#pragma unroll
    for (int sq2 = 0; sq2 < 2; ++sq2)
#pragma unroll
        for (int nt = 0; nt < 4; ++nt)
            b1v[sq2][nt] = b1[e * H_DIM + (hs * 2 + sq2) * HS + w * 64 + nt * 16 + l16];
    __builtin_amdgcn_sched_barrier(0);

    // ---- persistent output accumulator: y[64][512] over this H range ----
    f32x4 accY[4][4][2];
#pragma unroll
    for (int nc = 0; nc < 4; ++nc)
#pragma unroll
        for (int m = 0; m < 4; ++m)
#pragma unroll
            for (int nt = 0; nt < 2; ++nt)
                accY[nc][m][nt] = (f32x4){0.f, 0.f, 0.f, 0.f};

    // prologue: W(0)->b0, X(0)->a0, W(1)->b1   (queue: [b1v:8, W0:4, X0:1, W1:4])
    {
        const int si0 = hs * 2;
        W1CH(si0, 0, 0);
        XCH(0, 0);
        W1CH(si0, 1, 1);
    }

#pragma unroll
    for (int sq = 0; sq < 2; ++sq) {
        const int si = hs * 2 + sq;
        const int B = (sq == 0) ? 0 : 2;   // rotation base: (32*sq)%3

        // -------- GEMM1: h[64][256] = x-tile @ W1T-slice(si) --------
        f32x4 acc1[4][4];
#pragma unroll
        for (int m = 0; m < 4; ++m)
#pragma unroll
            for (int nt = 0; nt < 4; ++nt) acc1[m][nt] = (f32x4){0.f, 0.f, 0.f, 0.f};

#pragma unroll
        for (int u = 0; u < 16; ++u) {
            if (sq == 1 && u == 0)
                asm volatile("s_waitcnt vmcnt(0)" ::: "memory");  // si-pair entry
            else
                asm volatile("s_waitcnt vmcnt(4)" ::: "memory");  // leave W(u+1)
            BARX;
            if (u < 14)       { XCH(u + 1, (u + 1) & 1); W1CH(si, u + 2, (u + 2 + B) % 3); }
            else if (u == 14) { XCH(15, 1);              W2CH(si, 0, (16 + B) % 3); }
            else              {                          W2CH(si, 1, (17 + B) % 3); }

            const u16* Bp = &sB[(u + B) % 3][0];
            const u16* Ap = hTsA + (u & 1) * 2048;
            short8 bf[4], af[4];
#pragma unroll
            for (int nt = 0; nt < 4; ++nt) bf[nt] = *(const short8*)(Bp + fB1[nt]);
#pragma unroll
            for (int m = 0; m < 4; ++m)  af[m] = *(const short8*)(Ap + fA1[m]);
            __builtin_amdgcn_s_setprio(1);
#pragma unroll
            for (int nt = 0; nt < 4; ++nt)
#pragma unroll
                for (int m = 0; m < 4; ++m)
                    acc1[m][nt] = __builtin_amdgcn_mfma_f32_16x16x32_bf16(
                        af[m], bf[nt], acc1[m][nt], 0, 0, 0);
            __builtin_amdgcn_s_setprio(0);
        }

        // all waves done reading the x-dbuf region before hT overwrites it
        BARX;

        // -------- epilogue 1: bias + relu -> hT (bf16, XOR-swizzled) ------
#pragma unroll
        for (int nt = 0; nt < 4; ++nt) {
            const int c = w * 64 + nt * 16 + l16;
#pragma unroll
            for (int m = 0; m < 4; ++m)
#pragma unroll
                for (int r = 0; r < 4; ++r) {
                    const int row = m * 16 + quad * 4 + r;
                    const int sw  = ((quad * 4 + r) & 7) << 3;
                    hTsA[row * 256 + (c ^ sw)] =
                        bf16_rne(fmaxf(acc1[m][nt][r] + b1v[sq][nt], 0.f));
                }
        }
        asm volatile("s_waitcnt lgkmcnt(0)" ::: "memory");  // hT committed

        // -------- GEMM2: accY += hT @ W2T-slice(si) --------
#pragma unroll
        for (int v = 0; v < 16; ++v) {
            if (sq == 1 && v == 15)
                asm volatile("s_waitcnt vmcnt(0)" ::: "memory");  // final drain
            else
                asm volatile("s_waitcnt vmcnt(4)" ::: "memory");
            BARX;                               // v==0 also publishes hT
            if (v < 14)            W2CH(si, v + 2, (v + B) % 3);
            else if (sq == 0) {
                if (v == 14) W1CH(si + 1, 0, (2 + B) % 3);
                else         W1CH(si + 1, 1, (B) % 3);
            }

            const int nc = v >> 2, k2 = v & 3;
            const u16* Bp = &sB[(v + 1 + B) % 3][0];
#pragma unroll
            for (int kk = 0; kk < 2; ++kk) {
                const int cc = k2 * 64 + kk * 32;
                short8 a0 = *(const short8*)(hTsA + rowb[0] + ((cc + qoff) ^ hswz));
                short8 a1 = *(const short8*)(hTsA + rowb[1] + ((cc + qoff) ^ hswz));
                short8 a2 = *(const short8*)(hTsA + rowb[2] + ((cc + qoff) ^ hswz));
                short8 a3 = *(const short8*)(hTsA + rowb[3] + ((cc + qoff) ^ hswz));
                short8 b0  = *(const short8*)(Bp + fB2[0][kk]);
                short8 b1f = *(const short8*)(Bp + fB2[1][kk]);
                __builtin_amdgcn_s_setprio(1);
                accY[nc][0][0] = __builtin_amdgcn_mfma_f32_16x16x32_bf16(a0, b0,  accY[nc][0][0], 0, 0, 0);
                accY[nc][1][0] = __builtin_amdgcn_mfma_f32_16x16x32_bf16(a1, b0,  accY[nc][1][0], 0, 0, 0);
                accY[nc][2][0] = __builtin_amdgcn_mfma_f32_16x16x32_bf16(a2, b0,  accY[nc][2][0], 0, 0, 0);
                accY[nc][3][0] = __builtin_amdgcn_mfma_f32_16x16x32_bf16(a3, b0,  accY[nc][3][0], 0, 0, 0);
                accY[nc][0][1] = __builtin_amdgcn_mfma_f32_16x16x32_bf16(a0, b1f, accY[nc][0][1], 0, 0, 0);
                accY[nc][1][1] = __builtin_amdgcn_mfma_f32_16x16x32_bf16(a1, b1f, accY[nc][1][1], 0, 0, 0);
                accY[nc][2][1] = __builtin_amdgcn_mfma_f32_16x16x32_bf16(a2, b1f, accY[nc][2][1], 0, 0, 0);
                accY[nc][3][1] = __builtin_amdgcn_mfma_f32_16x16x32_bf16(a3, b1f, accY[nc][3][1], 0, 0, 0);
                __builtin_amdgcn_s_setprio(0);
            }
        }

        if (sq == 0) {
            BARX;           // hT reads done before x-dbuf overwrites region
            XCH(0, 0);      // refill x chunk 0 for next si
        }
    }

    // ---- epilogue: bf16 y partial write: (acc [+b2 at hs0]) * cw ----
    float cwv[4][4];
#pragma unroll
    for (int m = 0; m < 4; ++m)
#pragma unroll
        for (int r = 0; r < 4; ++r)
            cwv[m][r] = cwA[e * N_TOK + t * 64 + m * 16 + quad * 4 + r];

    u16* yT = y + (((size_t)e * 4 + hs) * YROWS + (size_t)t * 64) * D_IN;
#pragma unroll
    for (int nc = 0; nc < 4; ++nc)
#pragma unroll
        for (int nt = 0; nt < 2; ++nt) {
            const int dcol = nc * 128 + w * 32 + nt * 16 + l16;
            const float bias = (hs == 0) ? b2[e * D_IN + dcol] : 0.f;
#pragma unroll
            for (int m = 0; m < 4; ++m)
#pragma unroll
                for (int r = 0; r < 4; ++r) {
                    const int row = m * 16 + quad * 4 + r;
                    yT[(size_t)row * D_IN + dcol] =
                        bf16_rne((accY[nc][m][nt][r] + bias) * cwv[m][r]);
                }
        }
}

// ---------------------------------------------------------------------------
// Combine (mode3): out[t] = sum over k in {1,2}, hs in 0..3 of bf16 partials.
// ---------------------------------------------------------------------------
__global__ __launch_bounds__(256) void moe_combine_b4(
    const u16* __restrict__ y, const int* __restrict__ slotRec,
    const int2* __restrict__ recE, float* __restrict__ out)
{
    const int t  = blockIdx.x * 2 + (threadIdx.x >> 7);
    const int c4 = (threadIdx.x & 127) << 2;
    const int2 ee = recE[t];
    int s1 = slotRec[2 * t + 0];
    int s2 = slotRec[2 * t + 1];
    s1 = s1 < YROWS ? s1 : YROWS - 1;   // safety clamp
    s2 = s2 < YROWS ? s2 : YROWS - 1;
    float acc[4] = {0.f, 0.f, 0.f, 0.f};
#pragma unroll
    for (int h = 0; h < 4; ++h) {
        s16x4 a = *(const s16x4*)(
            y + (((size_t)ee.x * 4 + h) * YROWS + s1) * D_IN + c4);
        s16x4 bb = *(const s16x4*)(
            y + (((size_t)ee.y * 4 + h) * YROWS + s2) * D_IN + c4);
#pragma unroll
        for (int j = 0; j < 4; ++j)
            acc[j] += bf16_to_f32((u16)a[j]) + bf16_to_f32((u16)bb[j]);
    }
    *(float4*)(out + (size_t)t * D_IN + c4) =
        make_float4(acc[0], acc[1], acc[2], acc[3]);
}

// ---------------------------------------------------------------------------
// mode2 fallback: r8 SPLIT=1 TM=32 kernel (known-passing), f32 y.
// ---------------------------------------------------------------------------
#define STG1(si_, ks_, buf_)                                                  \
    do {                                                                      \
        const u16* _s = w1E + (size_t)(si_) * (HS * D_IN) + (ks_) * 32;       \
        _Pragma("unroll")                                                     \
        for (int _i = 0; _i < 4; ++_i)                                        \
            async16(_s + bOffB[_i], &sB[buf_][dstB + _i * 512]);              \
        if (w < 2)                                                            \
            async16(xb + aOffW + (ks_) * 32, &sA[buf_][w * 512 + lane * 8]);  \
    } while (0)

#define STG2(si_, u2_, buf_)                                                  \
    do {                                                                      \
        const int _nc = (u2_) >> 2, _k2 = (u2_) & 3;                          \
        const u16* _s = w2E + (size_t)_nc * (128 * H_DIM) + (si_) * HS + _k2 * 64; \
        _Pragma("unroll")                                                     \
        for (int _i = 0; _i < 4; ++_i)                                        \
            async16(_s + bOff2[_i], &sB[buf_][dstB + _i * 512]);              \
    } while (0)

__global__ __launch_bounds__(256, 2) void moe_expert_mfma2(
    const u16* __restrict__ xb,
    const u16* __restrict__ w1t, const u16* __restrict__ w2t,
    const float* __restrict__ b1, const float* __restrict__ b2,
    float* __restrict__ y,
    const int* __restrict__ counts, const int* __restrict__ lists,
    const float* __restrict__ cwA)
{
    const int b = blockIdx.x;
    const int e = b & 7;
    const int t = b >> 3;
    int cnt = counts[e];
    if (cnt > YROWS) cnt = YROWS;
    if (t * TM >= cnt) return;

    __shared__ __align__(16) u16 sB[3][8192];
    __shared__ __align__(16) u16 sA[3][1024];
    __shared__ __align__(16) u16 hT[TM * HROW];
    __shared__ int   tokS[TM];
    __shared__ float cwS[TM];

    const int tid  = threadIdx.x;
    const int w    = tid >> 6;
    const int lane = tid & 63;
    const int quad = lane >> 4;
    const int l16  = lane & 15;

    if (tid < TM) {
        int gi = t * TM + tid;
        bool v = gi < cnt;
        tokS[tid] = v ? lists[e * N_TOK + gi] : 0;
        cwS[tid]  = v ? cwA[e * N_TOK + gi] : 0.f;
    }
    __syncthreads();

    const int r4   = lane >> 2;
    const int csw1 = (lane & 3) ^ ((lane >> 4) & 3);
    const int r8   = lane >> 3;
    const int csw2 = (lane & 7) ^ r8;
    const int dstB = w * 2048 + lane * 8;

    int fB1[4], fA1[2];
#pragma unroll
    for (int nt = 0; nt < 4; ++nt) {
        int r = w * 64 + nt * 16 + l16;
        fB1[nt] = r * 32 + (quad ^ ((l16 >> 2) & 3)) * 8;
    }
#pragma unroll
    for (int m = 0; m < 2; ++m) {
        int r = m * 16 + l16;
        fA1[m] = r * 32 + (quad ^ ((l16 >> 2) & 3)) * 8;
    }
    int fB2[2][2], fA2[2];
#pragma unroll
    for (int nt = 0; nt < 2; ++nt)
#pragma unroll
        for (int kk = 0; kk < 2; ++kk) {
            int r = w * 32 + nt * 16 + l16;
            fB2[nt][kk] = r * 64 + (((kk * 4 + quad) ^ (l16 & 7)) * 8);
        }
#pragma unroll
    for (int m = 0; m < 2; ++m)
        fA2[m] = (m * 16 + l16) * HROW + quad * 8;

    const u16* w1E = w1t + (size_t)e * H_DIM * D_IN;
    const u16* w2E = w2t + (size_t)e * D_IN * H_DIM;
    int bOffB[4];
#pragma unroll
    for (int i = 0; i < 4; ++i)
        bOffB[i] = (w * 64 + i * 16 + r4) * D_IN + csw1 * 8;
    int bOff2[4];
#pragma unroll
    for (int i = 0; i < 4; ++i)
        bOff2[i] = (w * 32 + i * 8 + r8) * H_DIM + csw2 * 8;
    int aOffW = 0;
    if (w < 2) aOffW = tokS[w * 16 + r4] * D_IN + csw1 * 8;

    f32x4 accY[4][2][2];
#pragma unroll
    for (int nc = 0; nc < 4; ++nc)
#pragma unroll
        for (int m = 0; m < 2; ++m)
#pragma unroll
            for (int nt = 0; nt < 2; ++nt)
                accY[nc][m][nt] = (f32x4){0.f, 0.f, 0.f, 0.f};

    for (int si = 0; si < 8; ++si) {
        float b1v[4];
#pragma unroll
        for (int nt = 0; nt < 4; ++nt)
            b1v[nt] = b1[e * H_DIM + si * HS + w * 64 + nt * 16 + l16];

        STG1(si, 0, 0);

        f32x4 acc1[2][4];
#pragma unroll
        for (int m = 0; m < 2; ++m)
#pragma unroll
            for (int nt = 0; nt < 4; ++nt) acc1[m][nt] = (f32x4){0.f, 0.f, 0.f, 0.f};

#pragma unroll
        for (int u = 0; u < 16; ++u) {
            if (u == 0) {
                asm volatile("s_waitcnt vmcnt(0)" ::: "memory");
            } else if (u < 15) {
                if (w < 2) asm volatile("s_waitcnt vmcnt(5)" ::: "memory");
                else       asm volatile("s_waitcnt vmcnt(4)" ::: "memory");
            } else {
                asm volatile("s_waitcnt vmcnt(4)" ::: "memory");
            }
            BARX;
            if (u == 0)       { STG1(si, 1, 1); STG1(si, 2, 2); }
            else if (u < 14)  { STG1(si, u + 2, (u + 2) % 3); }
            else if (u == 14) { STG2(si, 0, 1); }
            else              { STG2(si, 1, 2); }

            const u16* Bp = &sB[u % 3][0];
            const u16* Ap = &sA[u % 3][0];
            short8 bf[4], af[2];
#pragma unroll
            for (int nt = 0; nt < 4; ++nt) bf[nt] = *(const short8*)(Bp + fB1[nt]);
#pragma unroll
            for (int m = 0; m < 2; ++m)  af[m] = *(const short8*)(Ap + fA1[m]);
            __builtin_amdgcn_s_setprio(1);
#pragma unroll
            for (int nt = 0; nt < 4; ++nt)
#pragma unroll
                for (int m = 0; m < 2; ++m)
                    acc1[m][nt] = __builtin_amdgcn_mfma_f32_16x16x32_bf16(
                        af[m], bf[nt], acc1[m][nt], 0, 0, 0);
            __builtin_amdgcn_s_setprio(0);
        }

#pragma unroll
        for (int nt = 0; nt < 4; ++nt) {
            const int c = w * 64 + nt * 16 + l16;
#pragma unroll
            for (int m = 0; m < 2; ++m)
#pragma unroll
                for (int r = 0; r < 4; ++r) {
                    int row = m * 16 + quad * 4 + r;
                    hT[row * HROW + c] = bf16_rne(fmaxf(acc1[m][nt][r] + b1v[nt], 0.f));
                }
        }

#pragma unroll
        for (int u = 0; u < 16; ++u) {
            if (u == 0)      asm volatile("s_waitcnt vmcnt(4) lgkmcnt(0)" ::: "memory");
            else if (u < 15) asm volatile("s_waitcnt vmcnt(4)" ::: "memory");
            else             asm volatile("s_waitcnt vmcnt(0)" ::: "memory");
            BARX;
            if (u < 14) STG2(si, u + 2, u % 3);

            const int nc = u >> 2, k2 = u & 3;
            const u16* Bp = &sB[(u + 1) % 3][0];
#pragma unroll
            for (int kk = 0; kk < 2; ++kk) {
                short8 a0  = *(const short8*)(hT + fA2[0] + k2 * 64 + kk * 32);
                short8 a1  = *(const short8*)(hT + fA2[1] + k2 * 64 + kk * 32);
                short8 b0  = *(const short8*)(Bp + fB2[0][kk]);
                short8 b1f = *(const short8*)(Bp + fB2[1][kk]);
                __builtin_amdgcn_s_setprio(1);
                accY[nc][0][0] = __builtin_amdgcn_mfma_f32_16x16x32_bf16(a0, b0,  accY[nc][0][0], 0, 0, 0);
                accY[nc][1][0] = __builtin_amdgcn_mfma_f32_16x16x32_bf16(a1, b0,  accY[nc][1][0], 0, 0, 0);
                accY[nc][0][1] = __builtin_amdgcn_mfma_f32_16x16x32_bf16(a0, b1f, accY[nc][0][1], 0, 0, 0);
                accY[nc][1][1] = __builtin_amdgcn_mfma_f32_16x16x32_bf16(a1, b1f, accY[nc][1][1], 0, 0, 0);
                __builtin_amdgcn_s_setprio(0);
            }
        }
    }

    float* yT = y + ((size_t)e * YROWS + (size_t)t * TM) * D_IN;
#pragma unroll
    for (int nc = 0; nc < 4; ++nc)
#pragma unroll
        for (int nt = 0; nt < 2; ++nt) {
            const int dcol = nc * 128 + w * 32 + nt * 16 + l16;
            const float bias = b2[e * D_IN + dcol];
#pragma unroll
            for (int m = 0; m < 2; ++m)
#pragma unroll
                for (int r = 0; r < 4; ++r) {
                    const int row = m * 16 + quad * 4 + r;
                    yT[(size_t)row * D_IN + dcol] =
                        (accY[nc][m][nt][r] + bias) * cwS[row];
                }
        }
}

// ---------------------------------------------------------------------------
// Combine (mode2): out[t] = y[e1][slot1] + y[e2][slot2]  (f32 y).
// ---------------------------------------------------------------------------
__global__ __launch_bounds__(256) void moe_combine_f1(
    const float* __restrict__ y, const int* __restrict__ slotRec,
    const int2* __restrict__ recE, float* __restrict__ out)
{
    const int t  = blockIdx.x * 2 + (threadIdx.x >> 7);
    const int c4 = (threadIdx.x & 127) << 2;
    const int2 ee = recE[t];
    int s1 = slotRec[2 * t + 0];
    int s2 = slotRec[2 * t + 1];
    s1 = s1 < YROWS ? s1 : YROWS - 1;
    s2 = s2 < YROWS ? s2 : YROWS - 1;
    const float4 a  = *(const float4*)(y + ((size_t)ee.x * YROWS + s1) * D_IN + c4);
    const float4 bb = *(const float4*)(y + ((size_t)ee.y * YROWS + s2) * D_IN + c4);
    *(float4*)(out + (size_t)t * D_IN + c4) =
        make_float4(a.x + bb.x, a.y + bb.y, a.z + bb.z, a.w + bb.w);
}

// ---------------------------------------------------------------------------
// r6 single-pass bf16 expert kernel (known-passing) — mode1 fallback.
// ---------------------------------------------------------------------------
__global__ __launch_bounds__(256, 4) void moe_expert_mfma(
    const u16* __restrict__ xb,
    const u16* __restrict__ w1t, const u16* __restrict__ w2t,
    const float* __restrict__ b1, const float* __restrict__ b2,
    float* __restrict__ out,
    const int* __restrict__ counts, const int* __restrict__ lists,
    const float* __restrict__ cwA)
{
    const int b = blockIdx.x;
    const int s = b & 7;
    const int q = b >> 3;
    const int t = q % MAXT;
    const int e = q / MAXT;
    const int cnt = counts[e];
    if (t * TM >= cnt) return;

    __shared__ __align__(16) u16 sB[8192];
    __shared__ __align__(16) u16 sA[1024];
    __shared__ __align__(16) u16 hT[TM * HROW];
    __shared__ int   tokS[TM];
    __shared__ float cwS[TM];

    const int tid  = threadIdx.x;
    const int w    = tid >> 6;
    const int lane = tid & 63;
    const int quad = lane >> 4;
    const int l16  = lane & 15;

    if (tid < TM) {
        int gi = t * TM + tid;
        bool v = gi < cnt;
        tokS[tid] = v ? lists[e * N_TOK + gi] : 0;
        cwS[tid]  = v ? cwA[e * N_TOK + gi] : 0.f;
    }
    __syncthreads();

    const int r4   = lane >> 2;
    const int csw1 = (lane & 3) ^ ((lane >> 4) & 3);
    const int r8   = lane >> 3;
    const int csw2 = (lane & 7) ^ r8;
    u16* ldsB0 = sB + w * 2048 + lane * 8;
    u16* ldsA0 = sA + lane * 8;

    int fB1[4], fA1[2];
#pragma unroll
    for (int nt = 0; nt < 4; ++nt) {
        int r = w * 64 + nt * 16 + l16;
        fB1[nt] = r * 32 + (quad ^ ((l16 >> 2) & 3)) * 8;
    }
#pragma unroll
    for (int m = 0; m < 2; ++m) {
        int r = m * 16 + l16;
        fA1[m] = r * 32 + (quad ^ ((l16 >> 2) & 3)) * 8;
    }
    int fB2[2][2], fA2[2];
#pragma unroll
    for (int nt = 0; nt < 2; ++nt)
#pragma unroll
        for (int kk = 0; kk < 2; ++kk) {
            int r = w * 32 + nt * 16 + l16;
            fB2[nt][kk] = r * 64 + (((kk * 4 + quad) ^ (l16 & 7)) * 8);
        }
#pragma unroll
    for (int m = 0; m < 2; ++m)
        fA2[m] = (m * 16 + l16) * HROW + quad * 8;

    int bOffB[4];
#pragma unroll
    for (int i = 0; i < 4; ++i)
        bOffB[i] = (s * HS + w * 64 + i * 16 + r4) * D_IN + csw1 * 8;
    int aOff0 = tokS[r4]      * D_IN + csw1 * 8;
    int aOff1 = tokS[16 + r4] * D_IN + csw1 * 8;
    const u16* w1E = w1t + (size_t)e * H_DIM * D_IN;

    f32x4 acc1[2][4];
#pragma unroll
    for (int m = 0; m < 2; ++m)
#pragma unroll
        for (int nt = 0; nt < 4; ++nt) acc1[m][nt] = (f32x4){0.f, 0.f, 0.f, 0.f};

    for (int ks = 0; ks < 16; ++ks) {
        const int kb = ks * 32;
        __syncthreads();
#pragma unroll
        for (int i = 0; i < 4; ++i)
            async16(w1E + bOffB[i] + kb, ldsB0 + i * 512);
        if (w == 0) {
            async16(xb + aOff0 + kb, ldsA0);
            async16(xb + aOff1 + kb, ldsA0 + 512);
        }
        __syncthreads();
        short8 bf[4], af[2];
#pragma unroll
        for (int nt = 0; nt < 4; ++nt) bf[nt] = *(const short8*)(sB + fB1[nt]);
#pragma unroll
        for (int m = 0; m < 2; ++m)  af[m] = *(const short8*)(sA + fA1[m]);
#pragma unroll
        for (int nt = 0; nt < 4; ++nt)
#pragma unroll
            for (int m = 0; m < 2; ++m)
                acc1[m][nt] = __builtin_amdgcn_mfma_f32_16x16x32_bf16(af[m], bf[nt], acc1[m][nt], 0, 0, 0);
    }

#pragma unroll
    for (int nt = 0; nt < 4; ++nt) {
        const int c = w * 64 + nt * 16 + l16;
        const float bias = b1[e * H_DIM + s * HS + c];
#pragma unroll
        for (int m = 0; m < 2; ++m)
#pragma unroll
            for (int r = 0; r < 4; ++r) {
                int row = m * 16 + quad * 4 + r;
                hT[row * HROW + c] = bf16_rne(fmaxf(acc1[m][nt][r] + bias, 0.f));
            }
    }

    const u16* w2E = w2t + (size_t)e * D_IN * H_DIM;
    int bOff2[4];
#pragma unroll
    for (int i = 0; i < 4; ++i)
        bOff2[i] = (w * 32 + i * 8 + r8) * H_DIM + s * HS + csw2 * 8;

    for (int nc = 0; nc < 4; ++nc) {
        f32x4 acc2[2][2];
#pragma unroll
        for (int m = 0; m < 2; ++m)
#pragma unroll
            for (int nt = 0; nt < 2; ++nt) acc2[m][nt] = (f32x4){0.f, 0.f, 0.f, 0.f};

        for (int ks = 0; ks < 4; ++ks) {
            __syncthreads();
#pragma unroll
            for (int i = 0; i < 4; ++i)
                async16(w2E + bOff2[i] + nc * (128 * H_DIM) + ks * 64,
                        ldsB0 + i * 512);
            __syncthreads();
#pragma unroll
            for (int kk = 0; kk < 2; ++kk) {
                short8 a0  = *(const short8*)(hT + fA2[0] + ks * 64 + kk * 32);
                short8 a1  = *(const short8*)(hT + fA2[1] + ks * 64 + kk * 32);
                short8 b0  = *(const short8*)(sB + fB2[0][kk]);
                short8 b1f = *(const short8*)(sB + fB2[1][kk]);
                acc2[0][0] = __builtin_amdgcn_mfma_f32_16x16x32_bf16(a0, b0,  acc2[0][0], 0, 0, 0);
                acc2[1][0] = __builtin_amdgcn_mfma_f32_16x16x32_bf16(a1, b0,  acc2[1][0], 0, 0, 0);
                acc2[0][1] = __builtin_amdgcn_mfma_f32_16x16x32_bf16(a0, b1f, acc2[0][1], 0, 0, 0);
                acc2[1][1] = __builtin_amdgcn_mfma_f32_16x16x32_bf16(a1, b1f, acc2[1][1], 0, 0, 0);
            }
        }

#pragma unroll
        for (int nt = 0; nt < 2; ++nt) {
            const int dcol = nc * 128 + w * 32 + nt * 16 + l16;
            const float bias = (s == 0) ? b2[e * D_IN + dcol] : 0.f;
#pragma unroll
            for (int m = 0; m < 2; ++m)
#pragma unroll
                for (int r = 0; r < 4; ++r) {
                    int row = m * 16 + quad * 4 + r;
                    float v = (acc2[m][nt][r] + bias) * cwS[row];
                    atomicAdd(out + (size_t)tokS[row] * D_IN + dcol, v);
                }
        }
    }
}

// ---------------------------------------------------------------------------
// Fallback fp32 expert kernel (round 1, known-passing) — mode0.
// ---------------------------------------------------------------------------
__global__ __launch_bounds__(256, 4) void moe_expert_fp32(
    const float* __restrict__ x,  const float* __restrict__ W1,
    const float* __restrict__ b1, const float* __restrict__ W2,
    const float* __restrict__ b2, float* __restrict__ out,
    const int* __restrict__ counts, const int* __restrict__ lists,
    const float* __restrict__ cwA)
{
    const int e    = blockIdx.x & 7;
    const int tile = blockIdx.x >> 3;
    const int cnt  = counts[e];
    if (tile * 16 >= cnt) return;

    __shared__ float xs[16 * 520];
    __shared__ float hs[16 * 68];
    __shared__ int   tokS[16];
    __shared__ float cwS[16];

    const int tid = threadIdx.x;
    if (tid < 16) {
        int gi = tile * 16 + tid;
        bool v = gi < cnt;
        tokS[tid] = v ? lists[e * N_TOK + gi] : 0;
        cwS[tid]  = v ? cwA[e * N_TOK + gi]  : 0.f;
    }
    __syncthreads();
    {
        const int i = tid >> 4, p = tid & 15;
        const float* xr = x + (size_t)tokS[i] * D_IN + p * 32;
        float* xd = xs + i * 520 + p * 32;
#pragma unroll
        for (int qq = 0; qq < 8; ++qq)
            *(float4*)(xd + qq * 4) = *(const float4*)(xr + qq * 4);
    }
    __syncthreads();

    const float* W1e = W1 + (size_t)e * D_IN * H_DIM;
    const float* W2e = W2 + (size_t)e * H_DIM * D_IN;
    const int j = tid & 31, rg1 = tid >> 5, cg = tid & 63, rg2 = tid >> 6;

    float acc[4][8];
#pragma unroll
    for (int i = 0; i < 4; ++i)
#pragma unroll
        for (int m = 0; m < 8; ++m) acc[i][m] = 0.f;

    for (int hc = 0; hc < H_DIM / 64; ++hc) {
        float a1[2][2] = {{0.f, 0.f}, {0.f, 0.f}};
        const float* w1p = W1e + hc * 64 + j;
        for (int d = 0; d < D_IN; d += 4) {
            float xv[2][4];
            *(float4*)xv[0] = *(const float4*)(xs + (rg1 * 2 + 0) * 520 + d);
            *(float4*)xv[1] = *(const float4*)(xs + (rg1 * 2 + 1) * 520 + d);
#pragma unroll
            for (int dd = 0; dd < 4; ++dd) {
                float wa = w1p[(size_t)(d + dd) * H_DIM];
                float wb = w1p[(size_t)(d + dd) * H_DIM + 32];
                a1[0][0] = fmaf(xv[0][dd], wa, a1[0][0]);
                a1[0][1] = fmaf(xv[0][dd], wb, a1[0][1]);
                a1[1][0] = fmaf(xv[1][dd], wa, a1[1][0]);
                a1[1][1] = fmaf(xv[1][dd], wb, a1[1][1]);
            }
        }
        float b1a = b1[e * H_DIM + hc * 64 + j];
        float b1b = b1[e * H_DIM + hc * 64 + j + 32];
        __syncthreads();
        hs[(rg1 * 2 + 0) * 68 + j]      = fmaxf(a1[0][0] + b1a, 0.f);
        hs[(rg1 * 2 + 0) * 68 + j + 32] = fmaxf(a1[0][1] + b1b, 0.f);
        hs[(rg1 * 2 + 1) * 68 + j]      = fmaxf(a1[1][0] + b1a, 0.f);
        hs[(rg1 * 2 + 1) * 68 + j + 32] = fmaxf(a1[1][1] + b1b, 0.f);
        __syncthreads();
        const float* w2p = W2e + (size_t)(hc * 64) * D_IN + cg;
        for (int k = 0; k < 64; k += 4) {
            float hv[4][4];
#pragma unroll
            for (int i = 0; i < 4; ++i)
                *(float4*)hv[i] = *(const float4*)(hs + (rg2 * 4 + i) * 68 + k);
#pragma unroll
            for (int kk = 0; kk < 4; ++kk) {
                float w2r[8];
#pragma unroll
                for (int m = 0; m < 8; ++m)
                    w2r[m] = w2p[(size_t)(k + kk) * D_IN + 64 * m];
#pragma unroll
                for (int i = 0; i < 4; ++i)
#pragma unroll
                    for (int m = 0; m < 8; ++m)
                        acc[i][m] = fmaf(hv[i][kk], w2r[m], acc[i][m]);
            }
        }
        __syncthreads();
    }
    float b2v[8];
#pragma unroll
    for (int m = 0; m < 8; ++m) b2v[m] = b2[e * D_IN + cg + 64 * m];
#pragma unroll
    for (int i = 0; i < 4; ++i) {
        const int r = rg2 * 4 + i;
        const float cw = cwS[r];
        float* op = out + (size_t)tokS[r] * D_IN + cg;
#pragma unroll
        for (int m = 0; m < 8; ++m)
            atomicAdd(op + 64 * m, (acc[i][m] + b2v[m]) * cw);
    }
}

// ---------------------------------------------------------------------------
extern "C" void kernel_launch(void* const* d_in, const int* in_sizes, int n_in,
                              void* d_out, int out_size, void* d_ws, size_t ws_size,
                              hipStream_t stream) {
    const float* x  = (const float*)d_in[0];
    const float* Wg = (const float*)d_in[1];
    const float* bg = (const float*)d_in[2];
    const float* W1 = (const float*)d_in[3];
    const float* b1 = (const float*)d_in[4];
    const float* W2 = (const float*)d_in[5];
    const float* b2 = (const float*)d_in[6];

    float* out   = (float*)d_out;
    float* gates = out + (size_t)N_TOK * D_IN;

    // ws layout: counts | recE | recG | lists | cw | xb | w1t | w2t | slot | y
    const size_t o_recE  = 1024;
    const size_t o_recG  = o_recE + (size_t)N_TOK * 8;
    const size_t o_lists = o_recG + (size_t)N_TOK * 8;
    const size_t o_cw    = o_lists + (size_t)N_EXP * N_TOK * 4;
    const size_t o_xb    = o_cw + (size_t)N_EXP * N_TOK * 4;
    const size_t o_w1t   = o_xb + (size_t)N_TOK * D_IN * 2;
    const size_t o_w2t   = o_w1t + (size_t)N_EXP * D_IN * H_DIM * 2;
    const size_t o_slot  = o_w2t + (size_t)N_EXP * D_IN * H_DIM * 2;
    const size_t o_y     = o_slot + (size_t)N_TOK * 2 * 4;
    const size_t ybytes1 = (size_t)N_EXP * YROWS * D_IN * 4;         // f32 SPLIT1
    const size_t ybytesb = (size_t)N_EXP * 4 * YROWS * D_IN * 2;     // bf16 SPLIT4
    const size_t NEED1   = o_slot;                                   // ~38.1 MB
    const size_t NEED2   = o_y + ybytes1;                            // ~59.1 MB
    const size_t NEED3   = o_y + ybytesb;                            // ~80.1 MB

    int*    counts  = (int*)d_ws;
    int2*   recE    = (int2*)((char*)d_ws + o_recE);
    float2* recG    = (float2*)((char*)d_ws + o_recG);
    int*    lists   = (int*)((char*)d_ws + o_lists);
    float*  cwA     = (float*)((char*)d_ws + o_cw);
    u16*    xb      = (u16*)((char*)d_ws + o_xb);
    u16*    w1t     = (u16*)((char*)d_ws + o_w1t);
    u16*    w2t     = (u16*)((char*)d_ws + o_w2t);
    int*    slotRec = (int*)((char*)d_ws + o_slot);
    float*  ywsF    = (float*)((char*)d_ws + o_y);
    u16*    ywsB    = (u16*)((char*)d_ws + o_y);

    const int mode = (ws_size >= NEED3) ? 3 :
                     (ws_size >= NEED2) ? 2 :
                     (ws_size >= NEED1) ? 1 : 0;
    const int nconv = (mode >= 1) ? 4096 : 0;
    const int nprep = nconv + N_TOK / 4;      // gate: 4 tokens/block, 4 waves

    moe_prep<<<nprep, 256, 0, stream>>>(
        W1, W2, w1t, w2t, nconv,
        x, Wg, bg, gates, recE, recG, xb, mode >= 1 ? 1 : 0, counts);
    build_lists<<<64, 256, 0, stream>>>(recE, recG, counts, lists, cwA,
                                        mode >= 2 ? slotRec : (int*)nullptr);

    if (mode == 3) {
        moe_expert_64b<<<N_EXP * 4 * MAXT64, 256, 0, stream>>>(
            xb, w1t, w2t, b1, b2, ywsB, counts, lists, cwA);
        moe_combine_b4<<<N_TOK / 2, 256, 0, stream>>>(ywsB, slotRec, recE, out);
    } else if (mode == 2) {
        moe_expert_mfma2<<<N_EXP * MAXT, 256, 0, stream>>>(
            xb, w1t, w2t, b1, b2, ywsF, counts, lists, cwA);
        moe_combine_f1<<<N_TOK / 2, 256, 0, stream>>>(ywsF, slotRec, recE, out);
    } else if (mode == 1) {
        hipMemsetAsync(d_out, 0, (size_t)N_TOK * D_IN * sizeof(float), stream);
        moe_expert_mfma<<<N_EXP * MAXT * 8, 256, 0, stream>>>(
            xb, w1t, w2t, b1, b2, out, counts, lists, cwA);
    } else {
        hipMemsetAsync(d_out, 0, (size_t)N_TOK * D_IN * sizeof(float), stream);
        moe_expert_fp32<<<N_EXP * 256, 256, 0, stream>>>(
            x, W1, b1, W2, b2, out, counts, lists, cwA);
    }
}